// Round 1
// baseline (1319.872 us; speedup 1.0000x reference)
//
#include <hip/hip_runtime.h>

// out[n,c] = sum_{e: dst[e]==n} ( sum_k x[src[e],k]*W3[k]*x[dst[e],k] ) * x[src[e],c] * W2[c]
// B=1, N=100000, E=1600000, C=128.

#define CCH 128

__global__ __launch_bounds__(256) void edge_gather_scatter(
    const float* __restrict__ x,          // [N, C]
    const int*   __restrict__ edge_index, // [2, E] : src row then dst row
    const float* __restrict__ W2,         // [C]
    const float* __restrict__ W3,         // [C]
    float*       __restrict__ out,        // [N, C]
    int E)
{
    const int gtid = blockIdx.x * blockDim.x + threadIdx.x;
    const int e    = gtid >> 6;          // one wave64 per edge
    const int lane = threadIdx.x & 63;   // lane owns channels 2*lane, 2*lane+1
    if (e >= E) return;

    const int s = edge_index[e];
    const int d = edge_index[E + e];

    const float2 xs = *reinterpret_cast<const float2*>(x + (size_t)s * CCH + lane * 2);
    const float2 xd = *reinterpret_cast<const float2*>(x + (size_t)d * CCH + lane * 2);
    const float2 w3 = *reinterpret_cast<const float2*>(W3 + lane * 2);
    const float2 w2 = *reinterpret_cast<const float2*>(W2 + lane * 2);

    // per-lane partial of the edge dot product
    float p = xs.x * w3.x * xd.x + xs.y * w3.y * xd.y;

    // wave64 butterfly reduce -> every lane holds w
    #pragma unroll
    for (int off = 32; off > 0; off >>= 1)
        p += __shfl_xor(p, off, 64);

    float* o = out + (size_t)d * CCH + lane * 2;
    atomicAdd(o,     p * xs.x * w2.x);
    atomicAdd(o + 1, p * xs.y * w2.y);
}

extern "C" void kernel_launch(void* const* d_in, const int* in_sizes, int n_in,
                              void* d_out, int out_size, void* d_ws, size_t ws_size,
                              hipStream_t stream) {
    const float* x          = (const float*)d_in[0];
    const int*   edge_index = (const int*)  d_in[1];
    const float* W2         = (const float*)d_in[2];
    const float* W3         = (const float*)d_in[3];
    float*       out        = (float*)d_out;

    const int E = in_sizes[1] / 2;

    // d_out is poisoned (0xAA) before timing and never re-poisoned between
    // replays: zero it every call so the atomic accumulation starts clean.
    hipMemsetAsync(d_out, 0, (size_t)out_size * sizeof(float), stream);

    // one wave (64 threads) per edge; 256-thread blocks = 4 edges/block
    const int edges_per_block = 256 / 64;
    const int grid = (E + edges_per_block - 1) / edges_per_block;
    edge_gather_scatter<<<grid, 256, 0, stream>>>(x, edge_index, W2, W3, out, E);
}

// Round 2
// 353.859 us; speedup vs baseline: 3.7299x; 3.7299x over previous
//
#include <hip/hip_runtime.h>

// out[n,c] = sum_{e: dst[e]==n} ( sum_k x[src[e],k]*W3[k]*x[dst[e],k] ) * x[src[e],c] * W2[c]
// B=1, N=100000, E=1600000, C=128.
//
// Strategy: counting-sort edges by dst (histogram -> exclusive scan -> scatter
// of src ids), then one wave64 per node gathers its edges, reduces in
// registers, and writes its 512B output row exactly once. No float atomics.

#define CCH 128
#define SCAN_BLOCK 256
#define SCAN_ITEMS 4            // 1024 elements per scan block
#define SCAN_TILE (SCAN_BLOCK * SCAN_ITEMS)

// ---------------- sort pipeline ----------------

__global__ void k_hist(const int* __restrict__ dst, int E, int* __restrict__ count) {
    int i = blockIdx.x * blockDim.x + threadIdx.x;
    int stride = gridDim.x * blockDim.x;
    for (; i < E; i += stride) atomicAdd(&count[dst[i]], 1);
}

// per-block exclusive scan over tiles of 1024; emits per-block total
__global__ void k_scan1(const int* __restrict__ count, int N,
                        int* __restrict__ partial, int* __restrict__ blocksum) {
    __shared__ int sdata[SCAN_BLOCK];
    const int base = blockIdx.x * SCAN_TILE;
    const int t = threadIdx.x;
    int v[SCAN_ITEMS];
    int local = 0;
    #pragma unroll
    for (int k = 0; k < SCAN_ITEMS; ++k) {
        int idx = base + t * SCAN_ITEMS + k;
        v[k] = (idx < N) ? count[idx] : 0;
        local += v[k];
    }
    sdata[t] = local;
    __syncthreads();
    #pragma unroll
    for (int off = 1; off < SCAN_BLOCK; off <<= 1) {
        int val = (t >= off) ? sdata[t - off] : 0;
        __syncthreads();
        sdata[t] += val;
        __syncthreads();
    }
    const int incl = sdata[t];
    int run = incl - local;          // exclusive prefix for this thread's chunk
    if (t == SCAN_BLOCK - 1) blocksum[blockIdx.x] = incl;
    #pragma unroll
    for (int k = 0; k < SCAN_ITEMS; ++k) {
        int idx = base + t * SCAN_ITEMS + k;
        if (idx < N) partial[idx] = run;
        run += v[k];
    }
}

// single-block exclusive scan of the (<=1024) block sums
__global__ void k_scan2(int* __restrict__ blocksum, int nb) {
    __shared__ int sdata[1024];
    const int t = threadIdx.x;
    const int v = (t < nb) ? blocksum[t] : 0;
    sdata[t] = v;
    __syncthreads();
    for (int off = 1; off < 1024; off <<= 1) {
        int val = (t >= off) ? sdata[t - off] : 0;
        __syncthreads();
        sdata[t] += val;
        __syncthreads();
    }
    if (t < nb) blocksum[t] = sdata[t] - v;   // exclusive
}

__global__ void k_scan3(const int* __restrict__ partial, const int* __restrict__ blocksum,
                        int N, int* __restrict__ offset, int* __restrict__ cursor) {
    int i = blockIdx.x * blockDim.x + threadIdx.x;
    if (i < N) {
        int o = partial[i] + blocksum[i / SCAN_TILE];
        offset[i] = o;
        cursor[i] = o;
    }
}

__global__ void k_scatter(const int* __restrict__ src, const int* __restrict__ dst, int E,
                          int* __restrict__ cursor, int* __restrict__ sorted_src) {
    int i = blockIdx.x * blockDim.x + threadIdx.x;
    int stride = gridDim.x * blockDim.x;
    for (; i < E; i += stride) {
        int pos = atomicAdd(&cursor[dst[i]], 1);
        sorted_src[pos] = src[i];
    }
}

// ---------------- accumulate: one wave64 per node ----------------

__global__ __launch_bounds__(256) void k_accum(
    const float* __restrict__ x,           // [N, C]
    const float* __restrict__ W2,          // [C]
    const float* __restrict__ W3,          // [C]
    const int*   __restrict__ offset,      // [N] start into sorted_src
    const int*   __restrict__ count,       // [N] degree
    const int*   __restrict__ sorted_src,  // [E]
    int N,
    float*       __restrict__ out)         // [N, C]
{
    const int n    = (blockIdx.x * blockDim.x + threadIdx.x) >> 6;
    const int lane = threadIdx.x & 63;
    if (n >= N) return;

    const float2 xd = *reinterpret_cast<const float2*>(x + (size_t)n * CCH + lane * 2);
    const float2 w3 = *reinterpret_cast<const float2*>(W3 + lane * 2);
    const float2 w2 = *reinterpret_cast<const float2*>(W2 + lane * 2);
    const float dx = w3.x * xd.x;      // fold: p = xs.x*dx + xs.y*dy
    const float dy = w3.y * xd.y;

    float2 acc = make_float2(0.f, 0.f);
    const int beg = offset[n];
    const int cnt = count[n];

    int j = 0;
    for (; j + 1 < cnt; j += 2) {      // 2 edges in flight to overlap shfl chains
        const int s0 = sorted_src[beg + j];
        const int s1 = sorted_src[beg + j + 1];
        const float2 a0 = *reinterpret_cast<const float2*>(x + (size_t)s0 * CCH + lane * 2);
        const float2 a1 = *reinterpret_cast<const float2*>(x + (size_t)s1 * CCH + lane * 2);
        float p0 = a0.x * dx + a0.y * dy;
        float p1 = a1.x * dx + a1.y * dy;
        #pragma unroll
        for (int off = 32; off > 0; off >>= 1) {
            p0 += __shfl_xor(p0, off, 64);
            p1 += __shfl_xor(p1, off, 64);
        }
        acc.x += p0 * a0.x + p1 * a1.x;
        acc.y += p0 * a0.y + p1 * a1.y;
    }
    if (j < cnt) {
        const int s0 = sorted_src[beg + j];
        const float2 a0 = *reinterpret_cast<const float2*>(x + (size_t)s0 * CCH + lane * 2);
        float p0 = a0.x * dx + a0.y * dy;
        #pragma unroll
        for (int off = 32; off > 0; off >>= 1) p0 += __shfl_xor(p0, off, 64);
        acc.x += p0 * a0.x;
        acc.y += p0 * a0.y;
    }

    acc.x *= w2.x;
    acc.y *= w2.y;
    *reinterpret_cast<float2*>(out + (size_t)n * CCH + lane * 2) = acc;
}

// ---------------- fallback (R0): float atomics ----------------

__global__ __launch_bounds__(256) void edge_gather_scatter(
    const float* __restrict__ x, const int* __restrict__ edge_index,
    const float* __restrict__ W2, const float* __restrict__ W3,
    float* __restrict__ out, int E)
{
    const int e    = (blockIdx.x * blockDim.x + threadIdx.x) >> 6;
    const int lane = threadIdx.x & 63;
    if (e >= E) return;
    const int s = edge_index[e];
    const int d = edge_index[E + e];
    const float2 xs = *reinterpret_cast<const float2*>(x + (size_t)s * CCH + lane * 2);
    const float2 xd = *reinterpret_cast<const float2*>(x + (size_t)d * CCH + lane * 2);
    const float2 w3 = *reinterpret_cast<const float2*>(W3 + lane * 2);
    const float2 w2 = *reinterpret_cast<const float2*>(W2 + lane * 2);
    float p = xs.x * w3.x * xd.x + xs.y * w3.y * xd.y;
    #pragma unroll
    for (int off = 32; off > 0; off >>= 1) p += __shfl_xor(p, off, 64);
    float* o = out + (size_t)d * CCH + lane * 2;
    atomicAdd(o,     p * xs.x * w2.x);
    atomicAdd(o + 1, p * xs.y * w2.y);
}

// ---------------- launch ----------------

extern "C" void kernel_launch(void* const* d_in, const int* in_sizes, int n_in,
                              void* d_out, int out_size, void* d_ws, size_t ws_size,
                              hipStream_t stream) {
    const float* x          = (const float*)d_in[0];
    const int*   edge_index = (const int*)  d_in[1];
    const float* W2         = (const float*)d_in[2];
    const float* W3         = (const float*)d_in[3];
    float*       out        = (float*)d_out;

    const int E = in_sizes[1] / 2;
    const int N = out_size / CCH;
    const int* src = edge_index;
    const int* dst = edge_index + E;

    // workspace layout (ints)
    const size_t nb_scan = (size_t)(N + SCAN_TILE - 1) / SCAN_TILE;   // <= 1024
    size_t need = ((size_t)3 * N + 1024 + (size_t)N /*partial*/ + (size_t)E) * 4;
    if (ws_size < need || nb_scan > 1024) {
        // fallback: atomic version
        hipMemsetAsync(d_out, 0, (size_t)out_size * sizeof(float), stream);
        const int grid = (E * 64 + 255) / 256;
        edge_gather_scatter<<<grid, 256, 0, stream>>>(x, edge_index, W2, W3, out, E);
        return;
    }

    int* w = (int*)d_ws;
    int* count      = w;              w += N;
    int* offset     = w;              w += N;
    int* cursor     = w;              w += N;
    int* partial    = w;              w += N;
    int* blocksum   = w;              w += 1024;
    int* sorted_src = w;              w += E;

    hipMemsetAsync(count, 0, (size_t)N * sizeof(int), stream);

    const int gsE = 2048;  // grid-stride blocks for edge-parallel kernels
    k_hist<<<gsE, 256, 0, stream>>>(dst, E, count);
    k_scan1<<<(int)nb_scan, SCAN_BLOCK, 0, stream>>>(count, N, partial, blocksum);
    k_scan2<<<1, 1024, 0, stream>>>(blocksum, (int)nb_scan);
    k_scan3<<<(N + 255) / 256, 256, 0, stream>>>(partial, blocksum, N, offset, cursor);
    k_scatter<<<gsE, 256, 0, stream>>>(src, dst, E, cursor, sorted_src);

    const int waves_per_block = 256 / 64;
    const int gridN = (N + waves_per_block - 1) / waves_per_block;
    k_accum<<<gridN, 256, 0, stream>>>(x, W2, W3, offset, count, sorted_src, N, out);
}

// Round 3
// 330.910 us; speedup vs baseline: 3.9886x; 1.0694x over previous
//
#include <hip/hip_runtime.h>
#include <hip/hip_fp16.h>

// out[n,c] = sum_{e: dst[e]==n} ( sum_k x[src[e],k]*W3[k]*x[dst[e],k] ) * x[src[e],c] * W2[c]
// B=1, N=100000, E=1600000, C=128.
//
// Counting-sort edges by dst, then one wave64 per node accumulates in
// registers and writes its row once. Gathered src rows are fp16-packed
// (halves the L3-bound random-gather traffic that dominates k_accum).

#define CCH 128
#define SCAN_BLOCK 256
#define SCAN_ITEMS 4            // 1024 elements per scan block
#define SCAN_TILE (SCAN_BLOCK * SCAN_ITEMS)

// ---------------- fp16 pack of x ----------------

__global__ __launch_bounds__(256) void k_pack(const float* __restrict__ x,
                                              __half* __restrict__ xh, int n4) {
    int i = blockIdx.x * blockDim.x + threadIdx.x;   // 4 floats per thread
    if (i >= n4) return;
    float4 v = reinterpret_cast<const float4*>(x)[i];
    __half2* o = reinterpret_cast<__half2*>(xh) + (size_t)i * 2;
    o[0] = __floats2half2_rn(v.x, v.y);
    o[1] = __floats2half2_rn(v.z, v.w);
}

// ---------------- sort pipeline ----------------

__global__ void k_hist(const int* __restrict__ dst, int E, int* __restrict__ count) {
    int i = blockIdx.x * blockDim.x + threadIdx.x;
    int stride = gridDim.x * blockDim.x;
    for (; i < E; i += stride) atomicAdd(&count[dst[i]], 1);
}

__global__ void k_scan1(const int* __restrict__ count, int N,
                        int* __restrict__ partial, int* __restrict__ blocksum) {
    __shared__ int sdata[SCAN_BLOCK];
    const int base = blockIdx.x * SCAN_TILE;
    const int t = threadIdx.x;
    int v[SCAN_ITEMS];
    int local = 0;
    #pragma unroll
    for (int k = 0; k < SCAN_ITEMS; ++k) {
        int idx = base + t * SCAN_ITEMS + k;
        v[k] = (idx < N) ? count[idx] : 0;
        local += v[k];
    }
    sdata[t] = local;
    __syncthreads();
    #pragma unroll
    for (int off = 1; off < SCAN_BLOCK; off <<= 1) {
        int val = (t >= off) ? sdata[t - off] : 0;
        __syncthreads();
        sdata[t] += val;
        __syncthreads();
    }
    const int incl = sdata[t];
    int run = incl - local;
    if (t == SCAN_BLOCK - 1) blocksum[blockIdx.x] = incl;
    #pragma unroll
    for (int k = 0; k < SCAN_ITEMS; ++k) {
        int idx = base + t * SCAN_ITEMS + k;
        if (idx < N) partial[idx] = run;
        run += v[k];
    }
}

__global__ void k_scan2(int* __restrict__ blocksum, int nb) {
    __shared__ int sdata[1024];
    const int t = threadIdx.x;
    const int v = (t < nb) ? blocksum[t] : 0;
    sdata[t] = v;
    __syncthreads();
    for (int off = 1; off < 1024; off <<= 1) {
        int val = (t >= off) ? sdata[t - off] : 0;
        __syncthreads();
        sdata[t] += val;
        __syncthreads();
    }
    if (t < nb) blocksum[t] = sdata[t] - v;
}

__global__ void k_scan3(const int* __restrict__ partial, const int* __restrict__ blocksum,
                        int N, int* __restrict__ offset, int* __restrict__ cursor) {
    int i = blockIdx.x * blockDim.x + threadIdx.x;
    if (i < N) {
        int o = partial[i] + blocksum[i / SCAN_TILE];
        offset[i] = o;
        cursor[i] = o;
    }
}

__global__ void k_scatter(const int* __restrict__ src, const int* __restrict__ dst, int E,
                          int* __restrict__ cursor, int* __restrict__ sorted_src) {
    int i = blockIdx.x * blockDim.x + threadIdx.x;
    int stride = gridDim.x * blockDim.x;
    for (; i < E; i += stride) {
        int pos = atomicAdd(&cursor[dst[i]], 1);
        sorted_src[pos] = src[i];
    }
}

// ---------------- accumulate: one wave64 per node, fp16 gathers ----------------

__global__ __launch_bounds__(256) void k_accum_f16(
    const float* __restrict__ x,           // [N, C] fp32 (dst rows, exact)
    const __half* __restrict__ xh,         // [N, C] fp16 (gathered src rows)
    const float* __restrict__ W2,
    const float* __restrict__ W3,
    const int*   __restrict__ offset,
    const int*   __restrict__ count,
    const int*   __restrict__ sorted_src,
    int N,
    float*       __restrict__ out)
{
    const int n    = (blockIdx.x * blockDim.x + threadIdx.x) >> 6;
    const int lane = threadIdx.x & 63;
    if (n >= N) return;

    const float2 xd = *reinterpret_cast<const float2*>(x + (size_t)n * CCH + lane * 2);
    const float2 w3 = *reinterpret_cast<const float2*>(W3 + lane * 2);
    const float2 w2 = *reinterpret_cast<const float2*>(W2 + lane * 2);
    const float dx = w3.x * xd.x;
    const float dy = w3.y * xd.y;

    const __half2* x2 = reinterpret_cast<const __half2*>(xh);  // node*64 + lane

    float2 acc = make_float2(0.f, 0.f);
    const int beg = offset[n];
    const int cnt = count[n];

    int j = 0;
    for (; j + 3 < cnt; j += 4) {          // 4 gathers in flight (latency-bound)
        const int s0 = sorted_src[beg + j];
        const int s1 = sorted_src[beg + j + 1];
        const int s2 = sorted_src[beg + j + 2];
        const int s3 = sorted_src[beg + j + 3];
        const float2 a0 = __half22float2(x2[(size_t)s0 * 64 + lane]);
        const float2 a1 = __half22float2(x2[(size_t)s1 * 64 + lane]);
        const float2 a2 = __half22float2(x2[(size_t)s2 * 64 + lane]);
        const float2 a3 = __half22float2(x2[(size_t)s3 * 64 + lane]);
        float p0 = a0.x * dx + a0.y * dy;
        float p1 = a1.x * dx + a1.y * dy;
        float p2 = a2.x * dx + a2.y * dy;
        float p3 = a3.x * dx + a3.y * dy;
        #pragma unroll
        for (int off = 32; off > 0; off >>= 1) {
            p0 += __shfl_xor(p0, off, 64);
            p1 += __shfl_xor(p1, off, 64);
            p2 += __shfl_xor(p2, off, 64);
            p3 += __shfl_xor(p3, off, 64);
        }
        acc.x += p0 * a0.x + p1 * a1.x + p2 * a2.x + p3 * a3.x;
        acc.y += p0 * a0.y + p1 * a1.y + p2 * a2.y + p3 * a3.y;
    }
    for (; j < cnt; ++j) {
        const int s0 = sorted_src[beg + j];
        const float2 a0 = __half22float2(x2[(size_t)s0 * 64 + lane]);
        float p0 = a0.x * dx + a0.y * dy;
        #pragma unroll
        for (int off = 32; off > 0; off >>= 1) p0 += __shfl_xor(p0, off, 64);
        acc.x += p0 * a0.x;
        acc.y += p0 * a0.y;
    }

    acc.x *= w2.x;
    acc.y *= w2.y;
    *reinterpret_cast<float2*>(out + (size_t)n * CCH + lane * 2) = acc;
}

// fp32-gather variant (fallback when ws too small for xh)
__global__ __launch_bounds__(256) void k_accum(
    const float* __restrict__ x, const float* __restrict__ W2, const float* __restrict__ W3,
    const int* __restrict__ offset, const int* __restrict__ count,
    const int* __restrict__ sorted_src, int N, float* __restrict__ out)
{
    const int n    = (blockIdx.x * blockDim.x + threadIdx.x) >> 6;
    const int lane = threadIdx.x & 63;
    if (n >= N) return;
    const float2 xd = *reinterpret_cast<const float2*>(x + (size_t)n * CCH + lane * 2);
    const float2 w3 = *reinterpret_cast<const float2*>(W3 + lane * 2);
    const float2 w2 = *reinterpret_cast<const float2*>(W2 + lane * 2);
    const float dx = w3.x * xd.x, dy = w3.y * xd.y;
    float2 acc = make_float2(0.f, 0.f);
    const int beg = offset[n], cnt = count[n];
    int j = 0;
    for (; j + 1 < cnt; j += 2) {
        const int s0 = sorted_src[beg + j];
        const int s1 = sorted_src[beg + j + 1];
        const float2 a0 = *reinterpret_cast<const float2*>(x + (size_t)s0 * CCH + lane * 2);
        const float2 a1 = *reinterpret_cast<const float2*>(x + (size_t)s1 * CCH + lane * 2);
        float p0 = a0.x * dx + a0.y * dy;
        float p1 = a1.x * dx + a1.y * dy;
        #pragma unroll
        for (int off = 32; off > 0; off >>= 1) {
            p0 += __shfl_xor(p0, off, 64);
            p1 += __shfl_xor(p1, off, 64);
        }
        acc.x += p0 * a0.x + p1 * a1.x;
        acc.y += p0 * a0.y + p1 * a1.y;
    }
    if (j < cnt) {
        const int s0 = sorted_src[beg + j];
        const float2 a0 = *reinterpret_cast<const float2*>(x + (size_t)s0 * CCH + lane * 2);
        float p0 = a0.x * dx + a0.y * dy;
        #pragma unroll
        for (int off = 32; off > 0; off >>= 1) p0 += __shfl_xor(p0, off, 64);
        acc.x += p0 * a0.x;
        acc.y += p0 * a0.y;
    }
    acc.x *= w2.x;
    acc.y *= w2.y;
    *reinterpret_cast<float2*>(out + (size_t)n * CCH + lane * 2) = acc;
}

// last-resort fallback: float atomics
__global__ __launch_bounds__(256) void edge_gather_scatter(
    const float* __restrict__ x, const int* __restrict__ edge_index,
    const float* __restrict__ W2, const float* __restrict__ W3,
    float* __restrict__ out, int E)
{
    const int e    = (blockIdx.x * blockDim.x + threadIdx.x) >> 6;
    const int lane = threadIdx.x & 63;
    if (e >= E) return;
    const int s = edge_index[e];
    const int d = edge_index[E + e];
    const float2 xs = *reinterpret_cast<const float2*>(x + (size_t)s * CCH + lane * 2);
    const float2 xd = *reinterpret_cast<const float2*>(x + (size_t)d * CCH + lane * 2);
    const float2 w3 = *reinterpret_cast<const float2*>(W3 + lane * 2);
    const float2 w2 = *reinterpret_cast<const float2*>(W2 + lane * 2);
    float p = xs.x * w3.x * xd.x + xs.y * w3.y * xd.y;
    #pragma unroll
    for (int off = 32; off > 0; off >>= 1) p += __shfl_xor(p, off, 64);
    float* o = out + (size_t)d * CCH + lane * 2;
    atomicAdd(o,     p * xs.x * w2.x);
    atomicAdd(o + 1, p * xs.y * w2.y);
}

// ---------------- launch ----------------

extern "C" void kernel_launch(void* const* d_in, const int* in_sizes, int n_in,
                              void* d_out, int out_size, void* d_ws, size_t ws_size,
                              hipStream_t stream) {
    const float* x          = (const float*)d_in[0];
    const int*   edge_index = (const int*)  d_in[1];
    const float* W2         = (const float*)d_in[2];
    const float* W3         = (const float*)d_in[3];
    float*       out        = (float*)d_out;

    const int E = in_sizes[1] / 2;
    const int N = out_size / CCH;
    const int* src = edge_index;
    const int* dst = edge_index + E;

    const size_t nb_scan = (size_t)(N + SCAN_TILE - 1) / SCAN_TILE;   // <= 1024
    const size_t int_bytes = ((size_t)4 * N + 1024 + (size_t)E) * 4;  // count,offset,cursor,partial,blocksum,sorted_src
    const size_t xh_bytes  = (size_t)N * CCH * 2;
    const size_t needA = xh_bytes + int_bytes;   // fp16-gather path
    const size_t needB = int_bytes;              // fp32-gather path

    if (nb_scan > 1024 || ws_size < needB) {
        hipMemsetAsync(d_out, 0, (size_t)out_size * sizeof(float), stream);
        const int grid = (E * 64 + 255) / 256;
        edge_gather_scatter<<<grid, 256, 0, stream>>>(x, edge_index, W2, W3, out, E);
        return;
    }

    const bool useF16 = (ws_size >= needA);
    char* base = (char*)d_ws;
    __half* xh = (__half*)base;
    int* w = (int*)(useF16 ? (base + xh_bytes) : base);
    int* count      = w;  w += N;
    int* offset     = w;  w += N;
    int* cursor     = w;  w += N;
    int* partial    = w;  w += N;
    int* blocksum   = w;  w += 1024;
    int* sorted_src = w;  w += E;

    hipMemsetAsync(count, 0, (size_t)N * sizeof(int), stream);

    if (useF16) {
        const int n4 = N * CCH / 4;
        k_pack<<<(n4 + 255) / 256, 256, 0, stream>>>(x, xh, n4);
    }

    const int gsE = 2048;
    k_hist<<<gsE, 256, 0, stream>>>(dst, E, count);
    k_scan1<<<(int)nb_scan, SCAN_BLOCK, 0, stream>>>(count, N, partial, blocksum);
    k_scan2<<<1, 1024, 0, stream>>>(blocksum, (int)nb_scan);
    k_scan3<<<(N + 255) / 256, 256, 0, stream>>>(partial, blocksum, N, offset, cursor);
    k_scatter<<<gsE, 256, 0, stream>>>(src, dst, E, cursor, sorted_src);

    const int gridN = (N + 3) / 4;   // 4 waves/block
    if (useF16) {
        k_accum_f16<<<gridN, 256, 0, stream>>>(x, xh, W2, W3, offset, count, sorted_src, N, out);
    } else {
        k_accum<<<gridN, 256, 0, stream>>>(x, W2, W3, offset, count, sorted_src, N, out);
    }
}

// Round 4
// 264.827 us; speedup vs baseline: 4.9839x; 1.2495x over previous
//
#include <hip/hip_runtime.h>
#include <hip/hip_fp16.h>

// out[n,c] = sum_{e: dst[e]==n} ( sum_k x[src[e],k]*W3[k]*x[dst[e],k] ) * x[src[e],c] * W2[c]
// B=1, N=100000, E=1600000, C=128.
//
// Pipeline: fp16-pack x; single-pass bucket scatter (pos=atomicAdd(cursor),
// bucket[dst*CAP+pos]=src, overflow->list); one wave64 per node accumulates
// from its bucket in registers and writes its row once; tiny atomic fixup for
// overflow edges. Fallback: R3 counting-sort pipeline, then pure atomics.

#define CCH 128
#define OVF_CAP 65536
#define SCAN_BLOCK 256
#define SCAN_ITEMS 4
#define SCAN_TILE (SCAN_BLOCK * SCAN_ITEMS)

// ---------------- fp16 pack of x ----------------

__global__ __launch_bounds__(256) void k_pack(const float* __restrict__ x,
                                              __half* __restrict__ xh, int n4) {
    int i = blockIdx.x * blockDim.x + threadIdx.x;
    if (i >= n4) return;
    float4 v = reinterpret_cast<const float4*>(x)[i];
    __half2* o = reinterpret_cast<__half2*>(xh) + (size_t)i * 2;
    o[0] = __floats2half2_rn(v.x, v.y);
    o[1] = __floats2half2_rn(v.z, v.w);
}

// ---------------- single-pass bucket scatter (8 edges/thread) ----------------

__global__ __launch_bounds__(256) void k_scatter8(
    const int* __restrict__ src, const int* __restrict__ dst, int E, int CAP,
    int* __restrict__ cursor, int* __restrict__ bucket,
    int* __restrict__ ovfcnt, int* __restrict__ ovflist)
{
    const int i = blockIdx.x * blockDim.x + threadIdx.x;
    const int base = i * 8;
    if (base + 8 <= E) {
        const int4 d0 = reinterpret_cast<const int4*>(dst)[i * 2];
        const int4 d1 = reinterpret_cast<const int4*>(dst)[i * 2 + 1];
        const int4 s0 = reinterpret_cast<const int4*>(src)[i * 2];
        const int4 s1 = reinterpret_cast<const int4*>(src)[i * 2 + 1];
        const int dd[8] = {d0.x, d0.y, d0.z, d0.w, d1.x, d1.y, d1.z, d1.w};
        const int sv[8] = {s0.x, s0.y, s0.z, s0.w, s1.x, s1.y, s1.z, s1.w};
        int pos[8];
        #pragma unroll
        for (int k = 0; k < 8; ++k) pos[k] = atomicAdd(&cursor[dd[k]], 1);  // 8 in flight
        #pragma unroll
        for (int k = 0; k < 8; ++k) {
            if (pos[k] < CAP) {
                bucket[(size_t)dd[k] * CAP + pos[k]] = sv[k];
            } else {
                int o = atomicAdd(ovfcnt, 1);
                if (o < OVF_CAP) { ovflist[2 * o] = sv[k]; ovflist[2 * o + 1] = dd[k]; }
            }
        }
    } else if (base < E) {
        for (int k = base; k < E; ++k) {
            const int d = dst[k], s = src[k];
            int pos = atomicAdd(&cursor[d], 1);
            if (pos < CAP) bucket[(size_t)d * CAP + pos] = s;
            else {
                int o = atomicAdd(ovfcnt, 1);
                if (o < OVF_CAP) { ovflist[2 * o] = s; ovflist[2 * o + 1] = d; }
            }
        }
    }
}

// ---------------- accumulate: one wave64 per node, fp16 gathers ----------------

__global__ __launch_bounds__(256) void k_accum_f16b(
    const float* __restrict__ x,
    const __half* __restrict__ xh,
    const float* __restrict__ W2,
    const float* __restrict__ W3,
    const int*   __restrict__ cursor,   // degree (may exceed CAP)
    const int*   __restrict__ bucket,   // [N, CAP] src ids
    int CAP, int N,
    float*       __restrict__ out)
{
    const int n    = (blockIdx.x * blockDim.x + threadIdx.x) >> 6;
    const int lane = threadIdx.x & 63;
    if (n >= N) return;

    const float2 xd = *reinterpret_cast<const float2*>(x + (size_t)n * CCH + lane * 2);
    const float2 w3 = *reinterpret_cast<const float2*>(W3 + lane * 2);
    const float2 w2 = *reinterpret_cast<const float2*>(W2 + lane * 2);
    const float dx = w3.x * xd.x;
    const float dy = w3.y * xd.y;

    const __half2* x2 = reinterpret_cast<const __half2*>(xh);

    int cnt = cursor[n];
    if (cnt > CAP) cnt = CAP;
    const int* bp = bucket + (size_t)n * CAP;

    float2 acc = make_float2(0.f, 0.f);
    int j = 0;
    for (; j + 3 < cnt; j += 4) {
        const int4 ss = *reinterpret_cast<const int4*>(bp + j);   // broadcast load
        const float2 a0 = __half22float2(x2[(size_t)ss.x * 64 + lane]);
        const float2 a1 = __half22float2(x2[(size_t)ss.y * 64 + lane]);
        const float2 a2 = __half22float2(x2[(size_t)ss.z * 64 + lane]);
        const float2 a3 = __half22float2(x2[(size_t)ss.w * 64 + lane]);
        float p0 = a0.x * dx + a0.y * dy;
        float p1 = a1.x * dx + a1.y * dy;
        float p2 = a2.x * dx + a2.y * dy;
        float p3 = a3.x * dx + a3.y * dy;
        #pragma unroll
        for (int off = 32; off > 0; off >>= 1) {
            p0 += __shfl_xor(p0, off, 64);
            p1 += __shfl_xor(p1, off, 64);
            p2 += __shfl_xor(p2, off, 64);
            p3 += __shfl_xor(p3, off, 64);
        }
        acc.x += p0 * a0.x + p1 * a1.x + p2 * a2.x + p3 * a3.x;
        acc.y += p0 * a0.y + p1 * a1.y + p2 * a2.y + p3 * a3.y;
    }
    for (; j < cnt; ++j) {
        const int s0 = bp[j];
        const float2 a0 = __half22float2(x2[(size_t)s0 * 64 + lane]);
        float p0 = a0.x * dx + a0.y * dy;
        #pragma unroll
        for (int off = 32; off > 0; off >>= 1) p0 += __shfl_xor(p0, off, 64);
        acc.x += p0 * a0.x;
        acc.y += p0 * a0.y;
    }

    acc.x *= w2.x;
    acc.y *= w2.y;
    *reinterpret_cast<float2*>(out + (size_t)n * CCH + lane * 2) = acc;
}

// ---------------- overflow fixup: fp32 atomics on the few spilled edges ----------------

__global__ __launch_bounds__(256) void k_fixup(
    const float* __restrict__ x, const float* __restrict__ W2, const float* __restrict__ W3,
    const int* __restrict__ ovfcnt, const int* __restrict__ ovflist,
    float* __restrict__ out)
{
    int m = *ovfcnt;
    if (m > OVF_CAP) m = OVF_CAP;
    const int w    = (blockIdx.x * blockDim.x + threadIdx.x) >> 6;
    const int lane = threadIdx.x & 63;
    const int nw   = (gridDim.x * blockDim.x) >> 6;
    for (int e = w; e < m; e += nw) {
        const int s = ovflist[2 * e];
        const int d = ovflist[2 * e + 1];
        const float2 xs = *reinterpret_cast<const float2*>(x + (size_t)s * CCH + lane * 2);
        const float2 xd = *reinterpret_cast<const float2*>(x + (size_t)d * CCH + lane * 2);
        const float2 w3 = *reinterpret_cast<const float2*>(W3 + lane * 2);
        const float2 w2 = *reinterpret_cast<const float2*>(W2 + lane * 2);
        float p = xs.x * w3.x * xd.x + xs.y * w3.y * xd.y;
        #pragma unroll
        for (int off = 32; off > 0; off >>= 1) p += __shfl_xor(p, off, 64);
        float* o = out + (size_t)d * CCH + lane * 2;
        atomicAdd(o,     p * xs.x * w2.x);
        atomicAdd(o + 1, p * xs.y * w2.y);
    }
}

// ---------------- fallback: R3 counting-sort pipeline ----------------

__global__ void k_hist(const int* __restrict__ dst, int E, int* __restrict__ count) {
    int i = blockIdx.x * blockDim.x + threadIdx.x;
    int stride = gridDim.x * blockDim.x;
    for (; i < E; i += stride) atomicAdd(&count[dst[i]], 1);
}

__global__ void k_scan1(const int* __restrict__ count, int N,
                        int* __restrict__ partial, int* __restrict__ blocksum) {
    __shared__ int sdata[SCAN_BLOCK];
    const int base = blockIdx.x * SCAN_TILE;
    const int t = threadIdx.x;
    int v[SCAN_ITEMS];
    int local = 0;
    #pragma unroll
    for (int k = 0; k < SCAN_ITEMS; ++k) {
        int idx = base + t * SCAN_ITEMS + k;
        v[k] = (idx < N) ? count[idx] : 0;
        local += v[k];
    }
    sdata[t] = local;
    __syncthreads();
    #pragma unroll
    for (int off = 1; off < SCAN_BLOCK; off <<= 1) {
        int val = (t >= off) ? sdata[t - off] : 0;
        __syncthreads();
        sdata[t] += val;
        __syncthreads();
    }
    const int incl = sdata[t];
    int run = incl - local;
    if (t == SCAN_BLOCK - 1) blocksum[blockIdx.x] = incl;
    #pragma unroll
    for (int k = 0; k < SCAN_ITEMS; ++k) {
        int idx = base + t * SCAN_ITEMS + k;
        if (idx < N) partial[idx] = run;
        run += v[k];
    }
}

__global__ void k_scan2(int* __restrict__ blocksum, int nb) {
    __shared__ int sdata[1024];
    const int t = threadIdx.x;
    const int v = (t < nb) ? blocksum[t] : 0;
    sdata[t] = v;
    __syncthreads();
    for (int off = 1; off < 1024; off <<= 1) {
        int val = (t >= off) ? sdata[t - off] : 0;
        __syncthreads();
        sdata[t] += val;
        __syncthreads();
    }
    if (t < nb) blocksum[t] = sdata[t] - v;
}

__global__ void k_scan3(const int* __restrict__ partial, const int* __restrict__ blocksum,
                        int N, int* __restrict__ offset, int* __restrict__ cursor) {
    int i = blockIdx.x * blockDim.x + threadIdx.x;
    if (i < N) {
        int o = partial[i] + blocksum[i / SCAN_TILE];
        offset[i] = o;
        cursor[i] = o;
    }
}

__global__ void k_scatter(const int* __restrict__ src, const int* __restrict__ dst, int E,
                          int* __restrict__ cursor, int* __restrict__ sorted_src) {
    int i = blockIdx.x * blockDim.x + threadIdx.x;
    int stride = gridDim.x * blockDim.x;
    for (; i < E; i += stride) {
        int pos = atomicAdd(&cursor[dst[i]], 1);
        sorted_src[pos] = src[i];
    }
}

__global__ __launch_bounds__(256) void k_accum_f16(
    const float* __restrict__ x, const __half* __restrict__ xh,
    const float* __restrict__ W2, const float* __restrict__ W3,
    const int* __restrict__ offset, const int* __restrict__ count,
    const int* __restrict__ sorted_src, int N, float* __restrict__ out)
{
    const int n    = (blockIdx.x * blockDim.x + threadIdx.x) >> 6;
    const int lane = threadIdx.x & 63;
    if (n >= N) return;
    const float2 xd = *reinterpret_cast<const float2*>(x + (size_t)n * CCH + lane * 2);
    const float2 w3 = *reinterpret_cast<const float2*>(W3 + lane * 2);
    const float2 w2 = *reinterpret_cast<const float2*>(W2 + lane * 2);
    const float dx = w3.x * xd.x, dy = w3.y * xd.y;
    const __half2* x2 = reinterpret_cast<const __half2*>(xh);
    float2 acc = make_float2(0.f, 0.f);
    const int beg = offset[n], cnt = count[n];
    int j = 0;
    for (; j + 3 < cnt; j += 4) {
        const int s0 = sorted_src[beg + j];
        const int s1 = sorted_src[beg + j + 1];
        const int s2 = sorted_src[beg + j + 2];
        const int s3 = sorted_src[beg + j + 3];
        const float2 a0 = __half22float2(x2[(size_t)s0 * 64 + lane]);
        const float2 a1 = __half22float2(x2[(size_t)s1 * 64 + lane]);
        const float2 a2 = __half22float2(x2[(size_t)s2 * 64 + lane]);
        const float2 a3 = __half22float2(x2[(size_t)s3 * 64 + lane]);
        float p0 = a0.x * dx + a0.y * dy;
        float p1 = a1.x * dx + a1.y * dy;
        float p2 = a2.x * dx + a2.y * dy;
        float p3 = a3.x * dx + a3.y * dy;
        #pragma unroll
        for (int off = 32; off > 0; off >>= 1) {
            p0 += __shfl_xor(p0, off, 64);
            p1 += __shfl_xor(p1, off, 64);
            p2 += __shfl_xor(p2, off, 64);
            p3 += __shfl_xor(p3, off, 64);
        }
        acc.x += p0 * a0.x + p1 * a1.x + p2 * a2.x + p3 * a3.x;
        acc.y += p0 * a0.y + p1 * a1.y + p2 * a2.y + p3 * a3.y;
    }
    for (; j < cnt; ++j) {
        const int s0 = sorted_src[beg + j];
        const float2 a0 = __half22float2(x2[(size_t)s0 * 64 + lane]);
        float p0 = a0.x * dx + a0.y * dy;
        #pragma unroll
        for (int off = 32; off > 0; off >>= 1) p0 += __shfl_xor(p0, off, 64);
        acc.x += p0 * a0.x;
        acc.y += p0 * a0.y;
    }
    acc.x *= w2.x;
    acc.y *= w2.y;
    *reinterpret_cast<float2*>(out + (size_t)n * CCH + lane * 2) = acc;
}

__global__ __launch_bounds__(256) void edge_gather_scatter(
    const float* __restrict__ x, const int* __restrict__ edge_index,
    const float* __restrict__ W2, const float* __restrict__ W3,
    float* __restrict__ out, int E)
{
    const int e    = (blockIdx.x * blockDim.x + threadIdx.x) >> 6;
    const int lane = threadIdx.x & 63;
    if (e >= E) return;
    const int s = edge_index[e];
    const int d = edge_index[E + e];
    const float2 xs = *reinterpret_cast<const float2*>(x + (size_t)s * CCH + lane * 2);
    const float2 xd = *reinterpret_cast<const float2*>(x + (size_t)d * CCH + lane * 2);
    const float2 w3 = *reinterpret_cast<const float2*>(W3 + lane * 2);
    const float2 w2 = *reinterpret_cast<const float2*>(W2 + lane * 2);
    float p = xs.x * w3.x * xd.x + xs.y * w3.y * xd.y;
    #pragma unroll
    for (int off = 32; off > 0; off >>= 1) p += __shfl_xor(p, off, 64);
    float* o = out + (size_t)d * CCH + lane * 2;
    atomicAdd(o,     p * xs.x * w2.x);
    atomicAdd(o + 1, p * xs.y * w2.y);
}

// ---------------- launch ----------------

extern "C" void kernel_launch(void* const* d_in, const int* in_sizes, int n_in,
                              void* d_out, int out_size, void* d_ws, size_t ws_size,
                              hipStream_t stream) {
    const float* x          = (const float*)d_in[0];
    const int*   edge_index = (const int*)  d_in[1];
    const float* W2         = (const float*)d_in[2];
    const float* W3         = (const float*)d_in[3];
    float*       out        = (float*)d_out;

    const int E = in_sizes[1] / 2;
    const int N = out_size / CCH;
    const int* src = edge_index;
    const int* dst = edge_index + E;

    const size_t xh_bytes = (size_t)N * CCH * 2;

    // ---- preferred: bucket path ----
    auto bucket_need = [&](int CAP) {
        return xh_bytes + (size_t)N * CAP * 4 + (size_t)N * 4 + 16 + (size_t)OVF_CAP * 8;
    };
    int CAP = 0;
    if      (ws_size >= bucket_need(64)) CAP = 64;
    else if (ws_size >= bucket_need(32)) CAP = 32;

    if (CAP > 0) {
        char* base = (char*)d_ws;
        __half* xh   = (__half*)base;                       base += xh_bytes;
        int* bucket  = (int*)base;                          base += (size_t)N * CAP * 4;
        int* cursor  = (int*)base;                          base += (size_t)N * 4;
        int* ovfcnt  = (int*)base;                          base += 16;
        int* ovflist = (int*)base;

        // zero cursor + ovfcnt in one shot (adjacent)
        hipMemsetAsync(cursor, 0, (size_t)N * 4 + 16, stream);

        const int n4 = N * CCH / 4;
        k_pack<<<(n4 + 255) / 256, 256, 0, stream>>>(x, xh, n4);

        const int nthr = (E + 7) / 8;
        k_scatter8<<<(nthr + 255) / 256, 256, 0, stream>>>(src, dst, E, CAP,
                                                           cursor, bucket, ovfcnt, ovflist);

        const int gridN = (N + 3) / 4;   // 4 waves/block
        k_accum_f16b<<<gridN, 256, 0, stream>>>(x, xh, W2, W3, cursor, bucket, CAP, N, out);

        k_fixup<<<128, 256, 0, stream>>>(x, W2, W3, ovfcnt, ovflist, out);
        return;
    }

    // ---- fallback: counting-sort pipeline (R3) ----
    const size_t nb_scan = (size_t)(N + SCAN_TILE - 1) / SCAN_TILE;
    const size_t int_bytes = ((size_t)4 * N + 1024 + (size_t)E) * 4;
    if (nb_scan <= 1024 && ws_size >= xh_bytes + int_bytes) {
        char* base = (char*)d_ws;
        __half* xh = (__half*)base;
        int* w = (int*)(base + xh_bytes);
        int* count      = w;  w += N;
        int* offset     = w;  w += N;
        int* cursor     = w;  w += N;
        int* partial    = w;  w += N;
        int* blocksum   = w;  w += 1024;
        int* sorted_src = w;  w += E;

        hipMemsetAsync(count, 0, (size_t)N * sizeof(int), stream);
        const int n4 = N * CCH / 4;
        k_pack<<<(n4 + 255) / 256, 256, 0, stream>>>(x, xh, n4);
        const int gsE = 2048;
        k_hist<<<gsE, 256, 0, stream>>>(dst, E, count);
        k_scan1<<<(int)nb_scan, SCAN_BLOCK, 0, stream>>>(count, N, partial, blocksum);
        k_scan2<<<1, 1024, 0, stream>>>(blocksum, (int)nb_scan);
        k_scan3<<<(N + 255) / 256, 256, 0, stream>>>(partial, blocksum, N, offset, cursor);
        k_scatter<<<gsE, 256, 0, stream>>>(src, dst, E, cursor, sorted_src);
        const int gridN = (N + 3) / 4;
        k_accum_f16<<<gridN, 256, 0, stream>>>(x, xh, W2, W3, offset, count, sorted_src, N, out);
        return;
    }

    // ---- last resort: pure atomics ----
    hipMemsetAsync(d_out, 0, (size_t)out_size * sizeof(float), stream);
    const int grid = (E * 64 + 255) / 256;
    edge_gather_scatter<<<grid, 256, 0, stream>>>(x, edge_index, W2, W3, out, E);
}

// Round 5
// 205.637 us; speedup vs baseline: 6.4185x; 1.2878x over previous
//
#include <hip/hip_runtime.h>
#include <hip/hip_fp16.h>

// out[n,c] = sum_{e: dst[e]==n} ( sum_k x[src[e],k]*W3[k]*x[dst[e],k] ) * x[src[e],c] * W2[c]
// B=1, N=100000, E=1600000, C=128.
//
// Pipeline (no global atomic-returns anywhere):
//   k_pack      : x fp32 -> fp16 (halves gather traffic)
//   k_hist_part : per-block LDS histogram over coarse bins (bin = dst>>6)
//   k_pscan1/2/3: exclusive scan of bin-major (bin,block) counts
//   k_place     : deterministic placement of packed (dstlow|src) into bins
//   k_sort_accum: per-bin LDS counting sort by dstlow + fused accumulation;
//                 each wave64 owns 16 nodes, fp16 gathers, one row-write/node
//   k_fixup_bins: fp32-atomic fixup for (never-expected) LDS overflow
// Fallback: R1-style pure-atomic kernel if constraints unmet.

#define CCH 128
#define BSHIFT 6
#define BWIDTH 64              // nodes per bin
#define MAXBIN 2048            // supports N <= 131072 (also needed for 17-bit src pack)
#define CH 4096                // edges per partition block
#define LDSCAP 2304            // max edges staged per bin (mean ~1024)
#define SCAN_BLOCK 256
#define SCAN_ITEMS 4
#define SCAN_TILE (SCAN_BLOCK * SCAN_ITEMS)

// ---------------- fp16 pack of x ----------------

__global__ __launch_bounds__(256) void k_pack(const float* __restrict__ x,
                                              __half* __restrict__ xh, int n4) {
    int i = blockIdx.x * blockDim.x + threadIdx.x;
    if (i >= n4) return;
    float4 v = reinterpret_cast<const float4*>(x)[i];
    __half2* o = reinterpret_cast<__half2*>(xh) + (size_t)i * 2;
    o[0] = __floats2half2_rn(v.x, v.y);
    o[1] = __floats2half2_rn(v.z, v.w);
}

// ---------------- B1: per-block histogram over coarse bins ----------------

__global__ __launch_bounds__(256) void k_hist_part(
    const int* __restrict__ dst, int E, int NBIN,
    int* __restrict__ hist_bm)           // [NBLK][NBIN] block-major (coalesced)
{
    __shared__ int cnt[MAXBIN];
    const int blk = blockIdx.x;
    const int tid = threadIdx.x;
    for (int b = tid; b < NBIN; b += 256) cnt[b] = 0;
    __syncthreads();

    const int e0 = blk * CH;
    #pragma unroll
    for (int k = 0; k < 4; ++k) {
        const int g = (e0 >> 2) + k * 256 + tid;   // int4 index
        const int e = g << 2;
        if (e >= E) continue;
        if (e + 4 <= E) {
            const int4 d4 = reinterpret_cast<const int4*>(dst)[g];
            atomicAdd(&cnt[d4.x >> BSHIFT], 1);
            atomicAdd(&cnt[d4.y >> BSHIFT], 1);
            atomicAdd(&cnt[d4.z >> BSHIFT], 1);
            atomicAdd(&cnt[d4.w >> BSHIFT], 1);
        } else {
            for (int ee = e; ee < E; ++ee) atomicAdd(&cnt[dst[ee] >> BSHIFT], 1);
        }
    }
    __syncthreads();
    int* hb = hist_bm + (size_t)blk * NBIN;
    for (int b = tid; b < NBIN; b += 256) hb[b] = cnt[b];
}

// ---------------- scan over bin-major flatten (gather-transposed read) ----------------

__global__ void k_pscan1(const int* __restrict__ hist_bm, int M, int NBIN, int NBLK,
                         int* __restrict__ partial, int* __restrict__ blocksum) {
    __shared__ int sdata[SCAN_BLOCK];
    const int base = blockIdx.x * SCAN_TILE;
    const int t = threadIdx.x;
    int v[SCAN_ITEMS];
    int local = 0;
    #pragma unroll
    for (int k = 0; k < SCAN_ITEMS; ++k) {
        int idx = base + t * SCAN_ITEMS + k;
        int val = 0;
        if (idx < M) {
            int bin = idx / NBLK, blk = idx % NBLK;
            val = hist_bm[(size_t)blk * NBIN + bin];
        }
        v[k] = val;
        local += val;
    }
    sdata[t] = local;
    __syncthreads();
    #pragma unroll
    for (int off = 1; off < SCAN_BLOCK; off <<= 1) {
        int val = (t >= off) ? sdata[t - off] : 0;
        __syncthreads();
        sdata[t] += val;
        __syncthreads();
    }
    const int incl = sdata[t];
    int run = incl - local;
    if (t == SCAN_BLOCK - 1) blocksum[blockIdx.x] = incl;
    #pragma unroll
    for (int k = 0; k < SCAN_ITEMS; ++k) {
        int idx = base + t * SCAN_ITEMS + k;
        if (idx < M) partial[idx] = run;
        run += v[k];
    }
}

__global__ void k_scan2(int* __restrict__ blocksum, int nb) {
    __shared__ int sdata[1024];
    const int t = threadIdx.x;
    const int v = (t < nb) ? blocksum[t] : 0;
    sdata[t] = v;
    __syncthreads();
    for (int off = 1; off < 1024; off <<= 1) {
        int val = (t >= off) ? sdata[t - off] : 0;
        __syncthreads();
        sdata[t] += val;
        __syncthreads();
    }
    if (t < nb) blocksum[t] = sdata[t] - v;
}

__global__ void k_pscan3(const int* __restrict__ partial, const int* __restrict__ blocksum,
                         int M, int* __restrict__ scanned) {
    int i = blockIdx.x * blockDim.x + threadIdx.x;
    if (i < M) scanned[i] = partial[i] + blocksum[i / SCAN_TILE];
}

// ---------------- B3: deterministic placement (LDS cursors, no global atomics) ----------------

__global__ __launch_bounds__(256) void k_place(
    const int* __restrict__ src, const int* __restrict__ dst, int E, int NBIN, int NBLK,
    const int* __restrict__ scanned, unsigned int* __restrict__ coarse)
{
    __shared__ int lcur[MAXBIN];
    const int blk = blockIdx.x;
    const int tid = threadIdx.x;
    for (int b = tid; b < NBIN; b += 256) lcur[b] = scanned[(size_t)b * NBLK + blk];
    __syncthreads();

    const int e0 = blk * CH;
    #pragma unroll
    for (int k = 0; k < 4; ++k) {
        const int g = (e0 >> 2) + k * 256 + tid;
        const int e = g << 2;
        if (e >= E) continue;
        if (e + 4 <= E) {
            const int4 d4 = reinterpret_cast<const int4*>(dst)[g];
            const int4 s4 = reinterpret_cast<const int4*>(src)[g];
            int p;
            p = atomicAdd(&lcur[d4.x >> BSHIFT], 1);
            coarse[p] = (unsigned)s4.x | ((unsigned)(d4.x & (BWIDTH - 1)) << 17);
            p = atomicAdd(&lcur[d4.y >> BSHIFT], 1);
            coarse[p] = (unsigned)s4.y | ((unsigned)(d4.y & (BWIDTH - 1)) << 17);
            p = atomicAdd(&lcur[d4.z >> BSHIFT], 1);
            coarse[p] = (unsigned)s4.z | ((unsigned)(d4.z & (BWIDTH - 1)) << 17);
            p = atomicAdd(&lcur[d4.w >> BSHIFT], 1);
            coarse[p] = (unsigned)s4.w | ((unsigned)(d4.w & (BWIDTH - 1)) << 17);
        } else {
            for (int ee = e; ee < E; ++ee) {
                const int d = dst[ee], s = src[ee];
                int p = atomicAdd(&lcur[d >> BSHIFT], 1);
                coarse[p] = (unsigned)s | ((unsigned)(d & (BWIDTH - 1)) << 17);
            }
        }
    }
}

// ---------------- C: per-bin LDS counting sort + fused accumulation ----------------

__global__ __launch_bounds__(256) void k_sort_accum(
    const float* __restrict__ x,
    const __half* __restrict__ xh,
    const float* __restrict__ W2,
    const float* __restrict__ W3,
    const unsigned int* __restrict__ coarse,
    const int* __restrict__ scanned,
    int NBIN, int NBLK, int E, int N,
    float* __restrict__ out)
{
    __shared__ unsigned int raw[LDSCAP];
    __shared__ int srcl[LDSCAP];
    __shared__ int cnt[BWIDTH], offs[BWIDTH], cur[BWIDTH];

    const int bin = blockIdx.x;
    const int tid = threadIdx.x;
    const int beg = scanned[(size_t)bin * NBLK];
    const int end = (bin + 1 < NBIN) ? scanned[(size_t)(bin + 1) * NBLK] : E;
    int m = end - beg;
    if (m > LDSCAP) m = LDSCAP;

    if (tid < BWIDTH) cnt[tid] = 0;
    __syncthreads();

    for (int i = tid; i < m; i += 256) {
        unsigned u = coarse[beg + i];
        raw[i] = u;
        atomicAdd(&cnt[u >> 17], 1);
    }
    __syncthreads();

    if (tid < 64) {            // wave 0: exclusive scan of 64 counts
        int c = cnt[tid];
        int v = c;
        #pragma unroll
        for (int d2 = 1; d2 < 64; d2 <<= 1) {
            int t2 = __shfl_up(v, d2, 64);
            if (tid >= d2) v += t2;
        }
        offs[tid] = v - c;
        cur[tid]  = v - c;
    }
    __syncthreads();

    for (int i = tid; i < m; i += 256) {
        unsigned u = raw[i];
        int p = atomicAdd(&cur[u >> 17], 1);
        srcl[p] = (int)(u & 0x1FFFFu);
    }
    __syncthreads();

    // accumulation: wave w owns nodes [w*16, w*16+16)
    const int w    = tid >> 6;
    const int lane = tid & 63;
    const float2 w3v = *reinterpret_cast<const float2*>(W3 + lane * 2);
    const float2 w2v = *reinterpret_cast<const float2*>(W2 + lane * 2);
    const __half2* x2 = reinterpret_cast<const __half2*>(xh);

    for (int i = 0; i < 16; ++i) {
        const int dl = w * 16 + i;
        const int node = (bin << BSHIFT) + dl;
        if (node >= N) break;                       // uniform across the wave

        const float2 xd = *reinterpret_cast<const float2*>(x + (size_t)node * CCH + lane * 2);
        const float dx = w3v.x * xd.x;
        const float dy = w3v.y * xd.y;

        float2 acc = make_float2(0.f, 0.f);
        const int b0 = offs[dl];
        const int c  = cnt[dl];
        int j = 0;
        for (; j + 3 < c; j += 4) {
            const int s0 = srcl[b0 + j];
            const int s1 = srcl[b0 + j + 1];
            const int s2 = srcl[b0 + j + 2];
            const int s3 = srcl[b0 + j + 3];
            const float2 a0 = __half22float2(x2[(size_t)s0 * 64 + lane]);
            const float2 a1 = __half22float2(x2[(size_t)s1 * 64 + lane]);
            const float2 a2 = __half22float2(x2[(size_t)s2 * 64 + lane]);
            const float2 a3 = __half22float2(x2[(size_t)s3 * 64 + lane]);
            float p0 = a0.x * dx + a0.y * dy;
            float p1 = a1.x * dx + a1.y * dy;
            float p2 = a2.x * dx + a2.y * dy;
            float p3 = a3.x * dx + a3.y * dy;
            #pragma unroll
            for (int off = 32; off > 0; off >>= 1) {
                p0 += __shfl_xor(p0, off, 64);
                p1 += __shfl_xor(p1, off, 64);
                p2 += __shfl_xor(p2, off, 64);
                p3 += __shfl_xor(p3, off, 64);
            }
            acc.x += p0 * a0.x + p1 * a1.x + p2 * a2.x + p3 * a3.x;
            acc.y += p0 * a0.y + p1 * a1.y + p2 * a2.y + p3 * a3.y;
        }
        for (; j < c; ++j) {
            const int s0 = srcl[b0 + j];
            const float2 a0 = __half22float2(x2[(size_t)s0 * 64 + lane]);
            float p0 = a0.x * dx + a0.y * dy;
            #pragma unroll
            for (int off = 32; off > 0; off >>= 1) p0 += __shfl_xor(p0, off, 64);
            acc.x += p0 * a0.x;
            acc.y += p0 * a0.y;
        }

        acc.x *= w2v.x;
        acc.y *= w2v.y;
        *reinterpret_cast<float2*>(out + (size_t)node * CCH + lane * 2) = acc;
    }
}

// ---------------- fixup for LDS-capacity overflow (expected: 0 edges) ----------------

__global__ __launch_bounds__(256) void k_fixup_bins(
    const float* __restrict__ x, const float* __restrict__ W2, const float* __restrict__ W3,
    const unsigned int* __restrict__ coarse, const int* __restrict__ scanned,
    int NBIN, int NBLK, int E, float* __restrict__ out)
{
    const int gw   = (blockIdx.x * blockDim.x + threadIdx.x) >> 6;
    const int lane = threadIdx.x & 63;
    const int nw   = (gridDim.x * blockDim.x) >> 6;
    const float2 w3v = *reinterpret_cast<const float2*>(W3 + lane * 2);
    const float2 w2v = *reinterpret_cast<const float2*>(W2 + lane * 2);
    for (int bin = gw; bin < NBIN; bin += nw) {
        const int beg = scanned[(size_t)bin * NBLK];
        const int end = (bin + 1 < NBIN) ? scanned[(size_t)(bin + 1) * NBLK] : E;
        for (int i = beg + LDSCAP; i < end; ++i) {
            const unsigned u = coarse[i];
            const int s = (int)(u & 0x1FFFFu);
            const int node = (bin << BSHIFT) + (int)(u >> 17);
            const float2 xs = *reinterpret_cast<const float2*>(x + (size_t)s * CCH + lane * 2);
            const float2 xd = *reinterpret_cast<const float2*>(x + (size_t)node * CCH + lane * 2);
            float p = xs.x * w3v.x * xd.x + xs.y * w3v.y * xd.y;
            #pragma unroll
            for (int off = 32; off > 0; off >>= 1) p += __shfl_xor(p, off, 64);
            float* o = out + (size_t)node * CCH + lane * 2;
            atomicAdd(o,     p * xs.x * w2v.x);
            atomicAdd(o + 1, p * xs.y * w2v.y);
        }
    }
}

// ---------------- last-resort fallback: pure fp32 atomics (R1) ----------------

__global__ __launch_bounds__(256) void edge_gather_scatter(
    const float* __restrict__ x, const int* __restrict__ edge_index,
    const float* __restrict__ W2, const float* __restrict__ W3,
    float* __restrict__ out, int E)
{
    const int e    = (blockIdx.x * blockDim.x + threadIdx.x) >> 6;
    const int lane = threadIdx.x & 63;
    if (e >= E) return;
    const int s = edge_index[e];
    const int d = edge_index[E + e];
    const float2 xs = *reinterpret_cast<const float2*>(x + (size_t)s * CCH + lane * 2);
    const float2 xd = *reinterpret_cast<const float2*>(x + (size_t)d * CCH + lane * 2);
    const float2 w3 = *reinterpret_cast<const float2*>(W3 + lane * 2);
    const float2 w2 = *reinterpret_cast<const float2*>(W2 + lane * 2);
    float p = xs.x * w3.x * xd.x + xs.y * w3.y * xd.y;
    #pragma unroll
    for (int off = 32; off > 0; off >>= 1) p += __shfl_xor(p, off, 64);
    float* o = out + (size_t)d * CCH + lane * 2;
    atomicAdd(o,     p * xs.x * w2.x);
    atomicAdd(o + 1, p * xs.y * w2.y);
}

// ---------------- launch ----------------

extern "C" void kernel_launch(void* const* d_in, const int* in_sizes, int n_in,
                              void* d_out, int out_size, void* d_ws, size_t ws_size,
                              hipStream_t stream) {
    const float* x          = (const float*)d_in[0];
    const int*   edge_index = (const int*)  d_in[1];
    const float* W2         = (const float*)d_in[2];
    const float* W3         = (const float*)d_in[3];
    float*       out        = (float*)d_out;

    const int E = in_sizes[1] / 2;
    const int N = out_size / CCH;
    const int* src = edge_index;
    const int* dst = edge_index + E;

    const int NBIN = (N + BWIDTH - 1) >> BSHIFT;
    const int NBLK = (E + CH - 1) / CH;
    const long long Mll = (long long)NBIN * NBLK;
    const int M = (int)Mll;
    const int nb1 = (M + SCAN_TILE - 1) / SCAN_TILE;

    const size_t xh_bytes = (size_t)N * CCH * 2;
    const size_t need = xh_bytes + (size_t)E * 4 + 3 * (size_t)M * 4 + 1024 * 4;

    const bool aligned16 = (((uintptr_t)src & 15) == 0) && (((uintptr_t)dst & 15) == 0);

    if (N <= (1 << 17) && NBIN <= MAXBIN && Mll <= (1LL << 20) && nb1 <= 1024 &&
        aligned16 && ws_size >= need) {
        char* base = (char*)d_ws;
        __half* xh       = (__half*)base;        base += xh_bytes;
        unsigned* coarse = (unsigned*)base;      base += (size_t)E * 4;
        int* hist_bm     = (int*)base;           base += (size_t)M * 4;
        int* partial     = (int*)base;           base += (size_t)M * 4;
        int* scanned     = (int*)base;           base += (size_t)M * 4;
        int* blocksum    = (int*)base;

        const int n4 = N * CCH / 4;
        k_pack<<<(n4 + 255) / 256, 256, 0, stream>>>(x, xh, n4);

        k_hist_part<<<NBLK, 256, 0, stream>>>(dst, E, NBIN, hist_bm);
        k_pscan1<<<nb1, SCAN_BLOCK, 0, stream>>>(hist_bm, M, NBIN, NBLK, partial, blocksum);
        k_scan2<<<1, 1024, 0, stream>>>(blocksum, nb1);
        k_pscan3<<<(M + 255) / 256, 256, 0, stream>>>(partial, blocksum, M, scanned);
        k_place<<<NBLK, 256, 0, stream>>>(src, dst, E, NBIN, NBLK, scanned, coarse);

        k_sort_accum<<<NBIN, 256, 0, stream>>>(x, xh, W2, W3, coarse, scanned,
                                               NBIN, NBLK, E, N, out);
        k_fixup_bins<<<128, 256, 0, stream>>>(x, W2, W3, coarse, scanned, NBIN, NBLK, E, out);
        return;
    }

    // last resort: pure atomics
    hipMemsetAsync(d_out, 0, (size_t)out_size * sizeof(float), stream);
    const int grid = (E * 64 + 255) / 256;
    edge_gather_scatter<<<grid, 256, 0, stream>>>(x, edge_index, W2, W3, out, E);
}

// Round 6
// 154.008 us; speedup vs baseline: 8.5701x; 1.3352x over previous
//
#include <hip/hip_runtime.h>
#include <hip/hip_fp16.h>

// out[n,c] = sum_{e: dst[e]==n} ( sum_k x[src[e],k]*W3[k]*x[dst[e],k] ) * x[src[e],c] * W2[c]
// B=1, N=100000, E=1600000, C=128.
//
// Pipeline (no global atomic-returns anywhere):
//   k_pack      : x fp32 -> fp16 (halves gather traffic)
//   k_hist_part : per-block LDS histogram over coarse bins (bin = dst>>6)
//   k_pscan1/2/3: exclusive scan of bin-major (bin,block) counts
//   k_place     : deterministic placement of packed (dstlow|src) into bins
//   k_sort_accum: per-bin LDS counting sort by dstlow + fused accumulation.
//                 NEW: 16 lanes per edge, 8 ch/lane, 16B gathers; 4 edges per
//                 wave per step -> 1 shfl-instr/edge instead of 6.
//   k_fixup_bins: fp32-atomic fixup for (never-expected) LDS overflow
// Fallback: R1-style pure-atomic kernel if constraints unmet.

#define CCH 128
#define BSHIFT 6
#define BWIDTH 64              // nodes per bin
#define MAXBIN 2048            // supports N <= 131072 (needed for 17-bit src pack)
#define CH 4096                // edges per partition block
#define LDSCAP 2304            // max edges staged per bin (mean ~1024)
#define SCAN_BLOCK 256
#define SCAN_ITEMS 4
#define SCAN_TILE (SCAN_BLOCK * SCAN_ITEMS)

// ---------------- fp16 pack of x ----------------

__global__ __launch_bounds__(256) void k_pack(const float* __restrict__ x,
                                              __half* __restrict__ xh, int n4) {
    int i = blockIdx.x * blockDim.x + threadIdx.x;
    if (i >= n4) return;
    float4 v = reinterpret_cast<const float4*>(x)[i];
    __half2* o = reinterpret_cast<__half2*>(xh) + (size_t)i * 2;
    o[0] = __floats2half2_rn(v.x, v.y);
    o[1] = __floats2half2_rn(v.z, v.w);
}

// ---------------- B1: per-block histogram over coarse bins ----------------

__global__ __launch_bounds__(256) void k_hist_part(
    const int* __restrict__ dst, int E, int NBIN,
    int* __restrict__ hist_bm)           // [NBLK][NBIN] block-major
{
    __shared__ int cnt[MAXBIN];
    const int blk = blockIdx.x;
    const int tid = threadIdx.x;
    for (int b = tid; b < NBIN; b += 256) cnt[b] = 0;
    __syncthreads();

    const int e0 = blk * CH;
    #pragma unroll
    for (int k = 0; k < 4; ++k) {
        const int g = (e0 >> 2) + k * 256 + tid;   // int4 index
        const int e = g << 2;
        if (e >= E) continue;
        if (e + 4 <= E) {
            const int4 d4 = reinterpret_cast<const int4*>(dst)[g];
            atomicAdd(&cnt[d4.x >> BSHIFT], 1);
            atomicAdd(&cnt[d4.y >> BSHIFT], 1);
            atomicAdd(&cnt[d4.z >> BSHIFT], 1);
            atomicAdd(&cnt[d4.w >> BSHIFT], 1);
        } else {
            for (int ee = e; ee < E; ++ee) atomicAdd(&cnt[dst[ee] >> BSHIFT], 1);
        }
    }
    __syncthreads();
    int* hb = hist_bm + (size_t)blk * NBIN;
    for (int b = tid; b < NBIN; b += 256) hb[b] = cnt[b];
}

// ---------------- scan over bin-major flatten ----------------

__global__ void k_pscan1(const int* __restrict__ hist_bm, int M, int NBIN, int NBLK,
                         int* __restrict__ partial, int* __restrict__ blocksum) {
    __shared__ int sdata[SCAN_BLOCK];
    const int base = blockIdx.x * SCAN_TILE;
    const int t = threadIdx.x;
    int v[SCAN_ITEMS];
    int local = 0;
    #pragma unroll
    for (int k = 0; k < SCAN_ITEMS; ++k) {
        int idx = base + t * SCAN_ITEMS + k;
        int val = 0;
        if (idx < M) {
            int bin = idx / NBLK, blk = idx % NBLK;
            val = hist_bm[(size_t)blk * NBIN + bin];
        }
        v[k] = val;
        local += val;
    }
    sdata[t] = local;
    __syncthreads();
    #pragma unroll
    for (int off = 1; off < SCAN_BLOCK; off <<= 1) {
        int val = (t >= off) ? sdata[t - off] : 0;
        __syncthreads();
        sdata[t] += val;
        __syncthreads();
    }
    const int incl = sdata[t];
    int run = incl - local;
    if (t == SCAN_BLOCK - 1) blocksum[blockIdx.x] = incl;
    #pragma unroll
    for (int k = 0; k < SCAN_ITEMS; ++k) {
        int idx = base + t * SCAN_ITEMS + k;
        if (idx < M) partial[idx] = run;
        run += v[k];
    }
}

__global__ void k_scan2(int* __restrict__ blocksum, int nb) {
    __shared__ int sdata[1024];
    const int t = threadIdx.x;
    const int v = (t < nb) ? blocksum[t] : 0;
    sdata[t] = v;
    __syncthreads();
    for (int off = 1; off < 1024; off <<= 1) {
        int val = (t >= off) ? sdata[t - off] : 0;
        __syncthreads();
        sdata[t] += val;
        __syncthreads();
    }
    if (t < nb) blocksum[t] = sdata[t] - v;
}

__global__ void k_pscan3(const int* __restrict__ partial, const int* __restrict__ blocksum,
                         int M, int* __restrict__ scanned) {
    int i = blockIdx.x * blockDim.x + threadIdx.x;
    if (i < M) scanned[i] = partial[i] + blocksum[i / SCAN_TILE];
}

// ---------------- B3: deterministic placement ----------------

__global__ __launch_bounds__(256) void k_place(
    const int* __restrict__ src, const int* __restrict__ dst, int E, int NBIN, int NBLK,
    const int* __restrict__ scanned, unsigned int* __restrict__ coarse)
{
    __shared__ int lcur[MAXBIN];
    const int blk = blockIdx.x;
    const int tid = threadIdx.x;
    for (int b = tid; b < NBIN; b += 256) lcur[b] = scanned[(size_t)b * NBLK + blk];
    __syncthreads();

    const int e0 = blk * CH;
    #pragma unroll
    for (int k = 0; k < 4; ++k) {
        const int g = (e0 >> 2) + k * 256 + tid;
        const int e = g << 2;
        if (e >= E) continue;
        if (e + 4 <= E) {
            const int4 d4 = reinterpret_cast<const int4*>(dst)[g];
            const int4 s4 = reinterpret_cast<const int4*>(src)[g];
            int p;
            p = atomicAdd(&lcur[d4.x >> BSHIFT], 1);
            coarse[p] = (unsigned)s4.x | ((unsigned)(d4.x & (BWIDTH - 1)) << 17);
            p = atomicAdd(&lcur[d4.y >> BSHIFT], 1);
            coarse[p] = (unsigned)s4.y | ((unsigned)(d4.y & (BWIDTH - 1)) << 17);
            p = atomicAdd(&lcur[d4.z >> BSHIFT], 1);
            coarse[p] = (unsigned)s4.z | ((unsigned)(d4.z & (BWIDTH - 1)) << 17);
            p = atomicAdd(&lcur[d4.w >> BSHIFT], 1);
            coarse[p] = (unsigned)s4.w | ((unsigned)(d4.w & (BWIDTH - 1)) << 17);
        } else {
            for (int ee = e; ee < E; ++ee) {
                const int d = dst[ee], s = src[ee];
                int p = atomicAdd(&lcur[d >> BSHIFT], 1);
                coarse[p] = (unsigned)s | ((unsigned)(d & (BWIDTH - 1)) << 17);
            }
        }
    }
}

// ---------------- C: per-bin LDS counting sort + fused accumulation ----------------
// Wave layout: wave g owns nodes g*16..g*16+15 of the bin. Within a wave,
// 4 groups of 16 lanes each own one edge per step; lane sl owns channels
// sl*8..sl*8+7 (16B fp16 gather). Reduce = 4 shfl_xor shared by all 4 edges.

__global__ __launch_bounds__(256) void k_sort_accum(
    const float* __restrict__ x,
    const __half* __restrict__ xh,
    const float* __restrict__ W2,
    const float* __restrict__ W3,
    const unsigned int* __restrict__ coarse,
    const int* __restrict__ scanned,
    int NBIN, int NBLK, int E, int N,
    float* __restrict__ out)
{
    __shared__ unsigned int raw[LDSCAP];
    __shared__ int srcl[LDSCAP];
    __shared__ int cnt[BWIDTH], offs[BWIDTH], cur[BWIDTH];

    const int bin = blockIdx.x;
    const int tid = threadIdx.x;
    const int beg = scanned[(size_t)bin * NBLK];
    const int end = (bin + 1 < NBIN) ? scanned[(size_t)(bin + 1) * NBLK] : E;
    int m = end - beg;
    if (m > LDSCAP) m = LDSCAP;

    if (tid < BWIDTH) cnt[tid] = 0;
    __syncthreads();

    for (int i = tid; i < m; i += 256) {
        unsigned u = coarse[beg + i];
        raw[i] = u;
        atomicAdd(&cnt[u >> 17], 1);
    }
    __syncthreads();

    if (tid < 64) {            // wave 0: exclusive scan of 64 counts
        int c = cnt[tid];
        int v = c;
        #pragma unroll
        for (int d2 = 1; d2 < 64; d2 <<= 1) {
            int t2 = __shfl_up(v, d2, 64);
            if (tid >= d2) v += t2;
        }
        offs[tid] = v - c;
        cur[tid]  = v - c;
    }
    __syncthreads();

    for (int i = tid; i < m; i += 256) {
        unsigned u = raw[i];
        int p = atomicAdd(&cur[u >> 17], 1);
        srcl[p] = (int)(u & 0x1FFFFu);
    }
    __syncthreads();

    const int w    = tid >> 6;       // wave id
    const int lane = tid & 63;
    const int grp  = lane >> 4;      // edge slot 0..3
    const int sl   = lane & 15;      // channel slot: ch sl*8..sl*8+7

    const float4 w3a = *reinterpret_cast<const float4*>(W3 + sl * 8);
    const float4 w3b = *reinterpret_cast<const float4*>(W3 + sl * 8 + 4);
    const float4 w2a = *reinterpret_cast<const float4*>(W2 + sl * 8);
    const float4 w2b = *reinterpret_cast<const float4*>(W2 + sl * 8 + 4);

    const char* xb = (const char*)xh;
    const int choff = sl << 4;       // byte offset of this lane's 16B within a row

    for (int i = 0; i < 16; ++i) {
        const int dl = w * 16 + i;
        const int node = (bin << BSHIFT) + dl;
        if (node >= N) break;                       // uniform across the wave

        // v = W3 .* x[node] for this lane's 8 channels (fp32, exact)
        const float4 xda = *reinterpret_cast<const float4*>(x + (size_t)node * CCH + sl * 8);
        const float4 xdb = *reinterpret_cast<const float4*>(x + (size_t)node * CCH + sl * 8 + 4);
        const float4 va = make_float4(w3a.x * xda.x, w3a.y * xda.y, w3a.z * xda.z, w3a.w * xda.w);
        const float4 vb = make_float4(w3b.x * xdb.x, w3b.y * xdb.y, w3b.z * xdb.z, w3b.w * xdb.w);

        float4 accA = make_float4(0.f, 0.f, 0.f, 0.f);
        float4 accB = make_float4(0.f, 0.f, 0.f, 0.f);

        const int b0 = offs[dl];
        const int c  = cnt[dl];

        int j = 0;
        for (; j + 8 <= c; j += 8) {               // 8 edges: 2 gathers in flight
            const int sA = srcl[b0 + j + grp];
            const int sB = srcl[b0 + j + 4 + grp];
            union { int4 i4; __half2 h[4]; } uA, uB;
            uA.i4 = *reinterpret_cast<const int4*>(xb + (((size_t)sA) << 8) + choff);
            uB.i4 = *reinterpret_cast<const int4*>(xb + (((size_t)sB) << 8) + choff);
            const float2 fA0 = __half22float2(uA.h[0]);
            const float2 fA1 = __half22float2(uA.h[1]);
            const float2 fA2 = __half22float2(uA.h[2]);
            const float2 fA3 = __half22float2(uA.h[3]);
            const float2 fB0 = __half22float2(uB.h[0]);
            const float2 fB1 = __half22float2(uB.h[1]);
            const float2 fB2 = __half22float2(uB.h[2]);
            const float2 fB3 = __half22float2(uB.h[3]);
            float pA = fA0.x * va.x + fA0.y * va.y + fA1.x * va.z + fA1.y * va.w
                     + fA2.x * vb.x + fA2.y * vb.y + fA3.x * vb.z + fA3.y * vb.w;
            float pB = fB0.x * va.x + fB0.y * va.y + fB1.x * va.z + fB1.y * va.w
                     + fB2.x * vb.x + fB2.y * vb.y + fB3.x * vb.z + fB3.y * vb.w;
            #pragma unroll
            for (int off = 1; off < 16; off <<= 1) {   // reduce within 16-lane group
                pA += __shfl_xor(pA, off, 64);
                pB += __shfl_xor(pB, off, 64);
            }
            accA.x += pA * fA0.x + pB * fB0.x;
            accA.y += pA * fA0.y + pB * fB0.y;
            accA.z += pA * fA1.x + pB * fB1.x;
            accA.w += pA * fA1.y + pB * fB1.y;
            accB.x += pA * fA2.x + pB * fB2.x;
            accB.y += pA * fA2.y + pB * fB2.y;
            accB.z += pA * fA3.x + pB * fB3.x;
            accB.w += pA * fA3.y + pB * fB3.y;
        }
        for (; j < c; j += 4) {                     // masked tail (<=2 iters)
            const bool ok = (j + grp) < c;
            const int s0 = ok ? srcl[b0 + j + grp] : srcl[b0];
            union { int4 i4; __half2 h[4]; } u0;
            u0.i4 = *reinterpret_cast<const int4*>(xb + (((size_t)s0) << 8) + choff);
            const float2 f0 = __half22float2(u0.h[0]);
            const float2 f1 = __half22float2(u0.h[1]);
            const float2 f2 = __half22float2(u0.h[2]);
            const float2 f3 = __half22float2(u0.h[3]);
            float p = f0.x * va.x + f0.y * va.y + f1.x * va.z + f1.y * va.w
                    + f2.x * vb.x + f2.y * vb.y + f3.x * vb.z + f3.y * vb.w;
            if (!ok) p = 0.f;
            #pragma unroll
            for (int off = 1; off < 16; off <<= 1) p += __shfl_xor(p, off, 64);
            accA.x += p * f0.x;
            accA.y += p * f0.y;
            accA.z += p * f1.x;
            accA.w += p * f1.y;
            accB.x += p * f2.x;
            accB.y += p * f2.y;
            accB.z += p * f3.x;
            accB.w += p * f3.y;
        }

        // combine the 4 group replicas (channels identical across groups)
        #pragma unroll
        for (int off = 16; off < 64; off <<= 1) {
            accA.x += __shfl_xor(accA.x, off, 64);
            accA.y += __shfl_xor(accA.y, off, 64);
            accA.z += __shfl_xor(accA.z, off, 64);
            accA.w += __shfl_xor(accA.w, off, 64);
            accB.x += __shfl_xor(accB.x, off, 64);
            accB.y += __shfl_xor(accB.y, off, 64);
            accB.z += __shfl_xor(accB.z, off, 64);
            accB.w += __shfl_xor(accB.w, off, 64);
        }

        // apply W2, then all 64 lanes write the 512B row: lane (grp,sl)
        // stores channels sl*8 + 2*grp, sl*8 + 2*grp + 1
        accA.x *= w2a.x; accA.y *= w2a.y; accA.z *= w2a.z; accA.w *= w2a.w;
        accB.x *= w2b.x; accB.y *= w2b.y; accB.z *= w2b.z; accB.w *= w2b.w;
        const float av[8] = {accA.x, accA.y, accA.z, accA.w, accB.x, accB.y, accB.z, accB.w};
        float2 st = make_float2(av[2 * grp], av[2 * grp + 1]);
        *reinterpret_cast<float2*>(out + (size_t)node * CCH + sl * 8 + 2 * grp) = st;
    }
}

// ---------------- fixup for LDS-capacity overflow (expected: 0 edges) ----------------

__global__ __launch_bounds__(256) void k_fixup_bins(
    const float* __restrict__ x, const float* __restrict__ W2, const float* __restrict__ W3,
    const unsigned int* __restrict__ coarse, const int* __restrict__ scanned,
    int NBIN, int NBLK, int E, float* __restrict__ out)
{
    const int gw   = (blockIdx.x * blockDim.x + threadIdx.x) >> 6;
    const int lane = threadIdx.x & 63;
    const int nw   = (gridDim.x * blockDim.x) >> 6;
    const float2 w3v = *reinterpret_cast<const float2*>(W3 + lane * 2);
    const float2 w2v = *reinterpret_cast<const float2*>(W2 + lane * 2);
    for (int bin = gw; bin < NBIN; bin += nw) {
        const int beg = scanned[(size_t)bin * NBLK];
        const int end = (bin + 1 < NBIN) ? scanned[(size_t)(bin + 1) * NBLK] : E;
        for (int i = beg + LDSCAP; i < end; ++i) {
            const unsigned u = coarse[i];
            const int s = (int)(u & 0x1FFFFu);
            const int node = (bin << BSHIFT) + (int)(u >> 17);
            const float2 xs = *reinterpret_cast<const float2*>(x + (size_t)s * CCH + lane * 2);
            const float2 xd = *reinterpret_cast<const float2*>(x + (size_t)node * CCH + lane * 2);
            float p = xs.x * w3v.x * xd.x + xs.y * w3v.y * xd.y;
            #pragma unroll
            for (int off = 32; off > 0; off >>= 1) p += __shfl_xor(p, off, 64);
            float* o = out + (size_t)node * CCH + lane * 2;
            atomicAdd(o,     p * xs.x * w2v.x);
            atomicAdd(o + 1, p * xs.y * w2v.y);
        }
    }
}

// ---------------- last-resort fallback: pure fp32 atomics (R1) ----------------

__global__ __launch_bounds__(256) void edge_gather_scatter(
    const float* __restrict__ x, const int* __restrict__ edge_index,
    const float* __restrict__ W2, const float* __restrict__ W3,
    float* __restrict__ out, int E)
{
    const int e    = (blockIdx.x * blockDim.x + threadIdx.x) >> 6;
    const int lane = threadIdx.x & 63;
    if (e >= E) return;
    const int s = edge_index[e];
    const int d = edge_index[E + e];
    const float2 xs = *reinterpret_cast<const float2*>(x + (size_t)s * CCH + lane * 2);
    const float2 xd = *reinterpret_cast<const float2*>(x + (size_t)d * CCH + lane * 2);
    const float2 w3 = *reinterpret_cast<const float2*>(W3 + lane * 2);
    const float2 w2 = *reinterpret_cast<const float2*>(W2 + lane * 2);
    float p = xs.x * w3.x * xd.x + xs.y * w3.y * xd.y;
    #pragma unroll
    for (int off = 32; off > 0; off >>= 1) p += __shfl_xor(p, off, 64);
    float* o = out + (size_t)d * CCH + lane * 2;
    atomicAdd(o,     p * xs.x * w2.x);
    atomicAdd(o + 1, p * xs.y * w2.y);
}

// ---------------- launch ----------------

extern "C" void kernel_launch(void* const* d_in, const int* in_sizes, int n_in,
                              void* d_out, int out_size, void* d_ws, size_t ws_size,
                              hipStream_t stream) {
    const float* x          = (const float*)d_in[0];
    const int*   edge_index = (const int*)  d_in[1];
    const float* W2         = (const float*)d_in[2];
    const float* W3         = (const float*)d_in[3];
    float*       out        = (float*)d_out;

    const int E = in_sizes[1] / 2;
    const int N = out_size / CCH;
    const int* src = edge_index;
    const int* dst = edge_index + E;

    const int NBIN = (N + BWIDTH - 1) >> BSHIFT;
    const int NBLK = (E + CH - 1) / CH;
    const long long Mll = (long long)NBIN * NBLK;
    const int M = (int)Mll;
    const int nb1 = (M + SCAN_TILE - 1) / SCAN_TILE;

    const size_t xh_bytes = (size_t)N * CCH * 2;
    const size_t need = xh_bytes + (size_t)E * 4 + 3 * (size_t)M * 4 + 1024 * 4;

    const bool aligned16 = (((uintptr_t)src & 15) == 0) && (((uintptr_t)dst & 15) == 0);

    if (N <= (1 << 17) && NBIN <= MAXBIN && Mll <= (1LL << 20) && nb1 <= 1024 &&
        aligned16 && ws_size >= need) {
        char* base = (char*)d_ws;
        __half* xh       = (__half*)base;        base += xh_bytes;
        unsigned* coarse = (unsigned*)base;      base += (size_t)E * 4;
        int* hist_bm     = (int*)base;           base += (size_t)M * 4;
        int* partial     = (int*)base;           base += (size_t)M * 4;
        int* scanned     = (int*)base;           base += (size_t)M * 4;
        int* blocksum    = (int*)base;

        const int n4 = N * CCH / 4;
        k_pack<<<(n4 + 255) / 256, 256, 0, stream>>>(x, xh, n4);

        k_hist_part<<<NBLK, 256, 0, stream>>>(dst, E, NBIN, hist_bm);
        k_pscan1<<<nb1, SCAN_BLOCK, 0, stream>>>(hist_bm, M, NBIN, NBLK, partial, blocksum);
        k_scan2<<<1, 1024, 0, stream>>>(blocksum, nb1);
        k_pscan3<<<(M + 255) / 256, 256, 0, stream>>>(partial, blocksum, M, scanned);
        k_place<<<NBLK, 256, 0, stream>>>(src, dst, E, NBIN, NBLK, scanned, coarse);

        k_sort_accum<<<NBIN, 256, 0, stream>>>(x, xh, W2, W3, coarse, scanned,
                                               NBIN, NBLK, E, N, out);
        k_fixup_bins<<<128, 256, 0, stream>>>(x, W2, W3, coarse, scanned, NBIN, NBLK, E, out);
        return;
    }

    // last resort: pure atomics
    hipMemsetAsync(d_out, 0, (size_t)out_size * sizeof(float), stream);
    const int grid = (E * 64 + 255) / 256;
    edge_gather_scatter<<<grid, 256, 0, stream>>>(x, edge_index, W2, W3, out, E);
}

// Round 7
// 147.450 us; speedup vs baseline: 8.9513x; 1.0445x over previous
//
#include <hip/hip_runtime.h>
#include <hip/hip_fp16.h>

// out[n,c] = sum_{e: dst[e]==n} ( sum_k x[src[e],k]*W3[k]*x[dst[e],k] ) * x[src[e],c] * W2[c]
// B=1, N=100000, E=1600000, C=128.
//
// Pipeline (5 launches, no global atomic-returns anywhere):
//   k_pack_hist : fused; x fp32->fp16 pack blocks + per-block coarse-bin
//                 histogram blocks (bin = dst>>5) running concurrently
//   k_pscan1/2  : exclusive scan of bin-major (bin,block) counts
//   k_place     : deterministic placement of packed (dstlow|src) into bins
//                 (scan offsets computed in-place from partial+blocksum)
//   k_sort_accum: per-bin LDS counting sort by dstlow + fused accumulation;
//                 16 lanes/edge, 8ch/lane, 16B fp16 gathers, 4 edges/wave-step;
//                 dst rows also read from fp16 xh; overflow folded in.
// BWIDTH=32 -> 3125 blocks, 10.6KB LDS/block -> ~2x concurrency vs R6.
// Fallback: R1-style pure-atomic kernel if constraints unmet.

#define CCH 128
#define BSHIFT 5
#define BWIDTH 32              // nodes per bin
#define MAXBIN 4096            // supports N <= 131072 (17-bit src pack)
#define CH 8192                // edges per partition block
#define LDSCAP 1280            // max edges staged per bin (mean ~512)
#define SCAN_BLOCK 256
#define SCAN_ITEMS 4
#define SCAN_TILE (SCAN_BLOCK * SCAN_ITEMS)

// ---------------- fused fp16 pack + per-block bin histogram ----------------

__global__ __launch_bounds__(256) void k_pack_hist(
    const float* __restrict__ x, __half* __restrict__ xh, int n4, int nPack,
    const int* __restrict__ dst, int E, int NBIN, int* __restrict__ hist_bm)
{
    __shared__ int cnt[MAXBIN];
    const int tid = threadIdx.x;

    if (blockIdx.x < nPack) {                 // pack role
        const int i = blockIdx.x * 256 + tid;
        if (i < n4) {
            float4 v = reinterpret_cast<const float4*>(x)[i];
            __half2* o = reinterpret_cast<__half2*>(xh) + (size_t)i * 2;
            o[0] = __floats2half2_rn(v.x, v.y);
            o[1] = __floats2half2_rn(v.z, v.w);
        }
        return;
    }

    const int blk = blockIdx.x - nPack;       // histogram role
    for (int b = tid; b < NBIN; b += 256) cnt[b] = 0;
    __syncthreads();

    const int e0 = blk * CH;
    #pragma unroll
    for (int k = 0; k < CH / 1024; ++k) {
        const int g = (e0 >> 2) + k * 256 + tid;   // int4 index
        const int e = g << 2;
        if (e >= E) continue;
        if (e + 4 <= E) {
            const int4 d4 = reinterpret_cast<const int4*>(dst)[g];
            atomicAdd(&cnt[d4.x >> BSHIFT], 1);
            atomicAdd(&cnt[d4.y >> BSHIFT], 1);
            atomicAdd(&cnt[d4.z >> BSHIFT], 1);
            atomicAdd(&cnt[d4.w >> BSHIFT], 1);
        } else {
            for (int ee = e; ee < E; ++ee) atomicAdd(&cnt[dst[ee] >> BSHIFT], 1);
        }
    }
    __syncthreads();
    int* hb = hist_bm + (size_t)blk * NBIN;
    for (int b = tid; b < NBIN; b += 256) hb[b] = cnt[b];
}

// ---------------- scan over bin-major flatten ----------------

__global__ void k_pscan1(const int* __restrict__ hist_bm, int M, int NBIN, int NBLK,
                         int* __restrict__ partial, int* __restrict__ blocksum) {
    __shared__ int sdata[SCAN_BLOCK];
    const int base = blockIdx.x * SCAN_TILE;
    const int t = threadIdx.x;
    int v[SCAN_ITEMS];
    int local = 0;
    #pragma unroll
    for (int k = 0; k < SCAN_ITEMS; ++k) {
        int idx = base + t * SCAN_ITEMS + k;
        int val = 0;
        if (idx < M) {
            int bin = idx / NBLK, blk = idx % NBLK;
            val = hist_bm[(size_t)blk * NBIN + bin];
        }
        v[k] = val;
        local += val;
    }
    sdata[t] = local;
    __syncthreads();
    #pragma unroll
    for (int off = 1; off < SCAN_BLOCK; off <<= 1) {
        int val = (t >= off) ? sdata[t - off] : 0;
        __syncthreads();
        sdata[t] += val;
        __syncthreads();
    }
    const int incl = sdata[t];
    int run = incl - local;
    if (t == SCAN_BLOCK - 1) blocksum[blockIdx.x] = incl;
    #pragma unroll
    for (int k = 0; k < SCAN_ITEMS; ++k) {
        int idx = base + t * SCAN_ITEMS + k;
        if (idx < M) partial[idx] = run;
        run += v[k];
    }
}

__global__ void k_scan2(int* __restrict__ blocksum, int nb) {
    __shared__ int sdata[1024];
    const int t = threadIdx.x;
    const int v = (t < nb) ? blocksum[t] : 0;
    sdata[t] = v;
    __syncthreads();
    for (int off = 1; off < 1024; off <<= 1) {
        int val = (t >= off) ? sdata[t - off] : 0;
        __syncthreads();
        sdata[t] += val;
        __syncthreads();
    }
    if (t < nb) blocksum[t] = sdata[t] - v;
}

// ---------------- deterministic placement ----------------

__global__ __launch_bounds__(256) void k_place(
    const int* __restrict__ src, const int* __restrict__ dst, int E, int NBIN, int NBLK,
    const int* __restrict__ partial, const int* __restrict__ blocksum,
    unsigned int* __restrict__ coarse)
{
    __shared__ int lcur[MAXBIN];
    const int blk = blockIdx.x;
    const int tid = threadIdx.x;
    for (int b = tid; b < NBIN; b += 256) {
        const size_t idx = (size_t)b * NBLK + blk;
        lcur[b] = partial[idx] + blocksum[idx / SCAN_TILE];
    }
    __syncthreads();

    const int e0 = blk * CH;
    #pragma unroll
    for (int k = 0; k < CH / 1024; ++k) {
        const int g = (e0 >> 2) + k * 256 + tid;
        const int e = g << 2;
        if (e >= E) continue;
        if (e + 4 <= E) {
            const int4 d4 = reinterpret_cast<const int4*>(dst)[g];
            const int4 s4 = reinterpret_cast<const int4*>(src)[g];
            int p;
            p = atomicAdd(&lcur[d4.x >> BSHIFT], 1);
            coarse[p] = (unsigned)s4.x | ((unsigned)(d4.x & (BWIDTH - 1)) << 17);
            p = atomicAdd(&lcur[d4.y >> BSHIFT], 1);
            coarse[p] = (unsigned)s4.y | ((unsigned)(d4.y & (BWIDTH - 1)) << 17);
            p = atomicAdd(&lcur[d4.z >> BSHIFT], 1);
            coarse[p] = (unsigned)s4.z | ((unsigned)(d4.z & (BWIDTH - 1)) << 17);
            p = atomicAdd(&lcur[d4.w >> BSHIFT], 1);
            coarse[p] = (unsigned)s4.w | ((unsigned)(d4.w & (BWIDTH - 1)) << 17);
        } else {
            for (int ee = e; ee < E; ++ee) {
                const int d = dst[ee], s = src[ee];
                int p = atomicAdd(&lcur[d >> BSHIFT], 1);
                coarse[p] = (unsigned)s | ((unsigned)(d & (BWIDTH - 1)) << 17);
            }
        }
    }
}

// ---------------- per-bin LDS counting sort + fused accumulation ----------------
// Wave w owns nodes w*8..w*8+7 of the bin. 4 groups of 16 lanes each own one
// edge per step; lane sl owns channels sl*8..sl*8+7 (16B fp16 loads).

__global__ __launch_bounds__(256) void k_sort_accum(
    const __half* __restrict__ xh,
    const float* __restrict__ W2,
    const float* __restrict__ W3,
    const unsigned int* __restrict__ coarse,
    const int* __restrict__ partial, const int* __restrict__ blocksum,
    int NBIN, int NBLK, int E, int N,
    float* __restrict__ out)
{
    __shared__ unsigned int raw[LDSCAP];
    __shared__ int srcl[LDSCAP];
    __shared__ int cnt[BWIDTH], offs[BWIDTH], cur[BWIDTH];

    const int bin = blockIdx.x;
    const int tid = threadIdx.x;
    const size_t i0 = (size_t)bin * NBLK;
    const int beg = partial[i0] + blocksum[i0 / SCAN_TILE];
    const int end = (bin + 1 < NBIN)
        ? partial[i0 + NBLK] + blocksum[(i0 + NBLK) / SCAN_TILE] : E;
    const int mtot = end - beg;
    const int m = (mtot < LDSCAP) ? mtot : LDSCAP;

    if (tid < BWIDTH) cnt[tid] = 0;
    __syncthreads();

    for (int i = tid; i < m; i += 256) {
        unsigned u = coarse[beg + i];
        raw[i] = u;
        atomicAdd(&cnt[u >> 17], 1);
    }
    __syncthreads();

    if (tid < BWIDTH) {          // lanes 0..31 of wave 0: exclusive scan
        int c = cnt[tid];
        int v = c;
        #pragma unroll
        for (int d2 = 1; d2 < BWIDTH; d2 <<= 1) {
            int t2 = __shfl_up(v, d2, 64);
            if (tid >= d2) v += t2;
        }
        offs[tid] = v - c;
        cur[tid]  = v - c;
    }
    __syncthreads();

    for (int i = tid; i < m; i += 256) {
        unsigned u = raw[i];
        int p = atomicAdd(&cur[u >> 17], 1);
        srcl[p] = (int)(u & 0x1FFFFu);
    }
    __syncthreads();

    const int w    = tid >> 6;       // wave id
    const int lane = tid & 63;
    const int grp  = lane >> 4;      // edge slot 0..3
    const int sl   = lane & 15;      // channel slot: ch sl*8..sl*8+7

    const float4 w3a = *reinterpret_cast<const float4*>(W3 + sl * 8);
    const float4 w3b = *reinterpret_cast<const float4*>(W3 + sl * 8 + 4);
    const float4 w2a = *reinterpret_cast<const float4*>(W2 + sl * 8);
    const float4 w2b = *reinterpret_cast<const float4*>(W2 + sl * 8 + 4);

    const char* xb = (const char*)xh;
    const int choff = sl << 4;       // byte offset of this lane's 16B within a row

    for (int i = 0; i < BWIDTH / 4; ++i) {
        const int dl = w * (BWIDTH / 4) + i;
        const int node = (bin << BSHIFT) + dl;
        if (node >= N) break;                       // uniform across the wave

        // v = W3 .* x[node] for this lane's 8 channels (dst row via fp16 xh)
        union { int4 i4; __half2 h[4]; } uD;
        uD.i4 = *reinterpret_cast<const int4*>(xb + (((size_t)node) << 8) + choff);
        const float2 e0 = __half22float2(uD.h[0]);
        const float2 e1 = __half22float2(uD.h[1]);
        const float2 e2 = __half22float2(uD.h[2]);
        const float2 e3 = __half22float2(uD.h[3]);
        const float4 va = make_float4(w3a.x * e0.x, w3a.y * e0.y, w3a.z * e1.x, w3a.w * e1.y);
        const float4 vb = make_float4(w3b.x * e2.x, w3b.y * e2.y, w3b.z * e3.x, w3b.w * e3.y);

        float4 accA = make_float4(0.f, 0.f, 0.f, 0.f);
        float4 accB = make_float4(0.f, 0.f, 0.f, 0.f);

        const int b0 = offs[dl];
        const int c  = cnt[dl];

        int j = 0;
        for (; j + 8 <= c; j += 8) {               // 8 edges: 2 gathers in flight
            const int sA = srcl[b0 + j + grp];
            const int sB = srcl[b0 + j + 4 + grp];
            union { int4 i4; __half2 h[4]; } uA, uB;
            uA.i4 = *reinterpret_cast<const int4*>(xb + (((size_t)sA) << 8) + choff);
            uB.i4 = *reinterpret_cast<const int4*>(xb + (((size_t)sB) << 8) + choff);
            const float2 fA0 = __half22float2(uA.h[0]);
            const float2 fA1 = __half22float2(uA.h[1]);
            const float2 fA2 = __half22float2(uA.h[2]);
            const float2 fA3 = __half22float2(uA.h[3]);
            const float2 fB0 = __half22float2(uB.h[0]);
            const float2 fB1 = __half22float2(uB.h[1]);
            const float2 fB2 = __half22float2(uB.h[2]);
            const float2 fB3 = __half22float2(uB.h[3]);
            float pA = fA0.x * va.x + fA0.y * va.y + fA1.x * va.z + fA1.y * va.w
                     + fA2.x * vb.x + fA2.y * vb.y + fA3.x * vb.z + fA3.y * vb.w;
            float pB = fB0.x * va.x + fB0.y * va.y + fB1.x * va.z + fB1.y * va.w
                     + fB2.x * vb.x + fB2.y * vb.y + fB3.x * vb.z + fB3.y * vb.w;
            #pragma unroll
            for (int off = 1; off < 16; off <<= 1) {   // reduce within 16-lane group
                pA += __shfl_xor(pA, off, 64);
                pB += __shfl_xor(pB, off, 64);
            }
            accA.x += pA * fA0.x + pB * fB0.x;
            accA.y += pA * fA0.y + pB * fB0.y;
            accA.z += pA * fA1.x + pB * fB1.x;
            accA.w += pA * fA1.y + pB * fB1.y;
            accB.x += pA * fA2.x + pB * fB2.x;
            accB.y += pA * fA2.y + pB * fB2.y;
            accB.z += pA * fA3.x + pB * fB3.x;
            accB.w += pA * fA3.y + pB * fB3.y;
        }
        for (; j < c; j += 4) {                     // masked tail (<=2 iters)
            const bool ok = (j + grp) < c;
            const int s0 = ok ? srcl[b0 + j + grp] : srcl[b0];
            union { int4 i4; __half2 h[4]; } u0;
            u0.i4 = *reinterpret_cast<const int4*>(xb + (((size_t)s0) << 8) + choff);
            const float2 f0 = __half22float2(u0.h[0]);
            const float2 f1 = __half22float2(u0.h[1]);
            const float2 f2 = __half22float2(u0.h[2]);
            const float2 f3 = __half22float2(u0.h[3]);
            float p = f0.x * va.x + f0.y * va.y + f1.x * va.z + f1.y * va.w
                    + f2.x * vb.x + f2.y * vb.y + f3.x * vb.z + f3.y * vb.w;
            if (!ok) p = 0.f;
            #pragma unroll
            for (int off = 1; off < 16; off <<= 1) p += __shfl_xor(p, off, 64);
            accA.x += p * f0.x;
            accA.y += p * f0.y;
            accA.z += p * f1.x;
            accA.w += p * f1.y;
            accB.x += p * f2.x;
            accB.y += p * f2.y;
            accB.z += p * f3.x;
            accB.w += p * f3.y;
        }
        // LDS-capacity overflow (normally zero iterations): scan spilled edges
        for (int i2 = LDSCAP; i2 < mtot; ++i2) {
            const unsigned u = coarse[beg + i2];
            if ((int)(u >> 17) != dl) continue;
            const int s0 = (int)(u & 0x1FFFFu);
            union { int4 i4; __half2 h[4]; } u0;
            u0.i4 = *reinterpret_cast<const int4*>(xb + (((size_t)s0) << 8) + choff);
            const float2 f0 = __half22float2(u0.h[0]);
            const float2 f1 = __half22float2(u0.h[1]);
            const float2 f2 = __half22float2(u0.h[2]);
            const float2 f3 = __half22float2(u0.h[3]);
            float p = f0.x * va.x + f0.y * va.y + f1.x * va.z + f1.y * va.w
                    + f2.x * vb.x + f2.y * vb.y + f3.x * vb.z + f3.y * vb.w;
            #pragma unroll
            for (int off = 1; off < 16; off <<= 1) p += __shfl_xor(p, off, 64);
            if (grp != 0) p = 0.f;   // count the edge exactly once across replicas
            accA.x += p * f0.x;
            accA.y += p * f0.y;
            accA.z += p * f1.x;
            accA.w += p * f1.y;
            accB.x += p * f2.x;
            accB.y += p * f2.y;
            accB.z += p * f3.x;
            accB.w += p * f3.y;
        }

        // combine the 4 group replicas (channels identical across groups)
        #pragma unroll
        for (int off = 16; off < 64; off <<= 1) {
            accA.x += __shfl_xor(accA.x, off, 64);
            accA.y += __shfl_xor(accA.y, off, 64);
            accA.z += __shfl_xor(accA.z, off, 64);
            accA.w += __shfl_xor(accA.w, off, 64);
            accB.x += __shfl_xor(accB.x, off, 64);
            accB.y += __shfl_xor(accB.y, off, 64);
            accB.z += __shfl_xor(accB.z, off, 64);
            accB.w += __shfl_xor(accB.w, off, 64);
        }

        // apply W2; lane (grp,sl) stores channels sl*8+2*grp, sl*8+2*grp+1
        accA.x *= w2a.x; accA.y *= w2a.y; accA.z *= w2a.z; accA.w *= w2a.w;
        accB.x *= w2b.x; accB.y *= w2b.y; accB.z *= w2b.z; accB.w *= w2b.w;
        const float av[8] = {accA.x, accA.y, accA.z, accA.w, accB.x, accB.y, accB.z, accB.w};
        float2 st = make_float2(av[2 * grp], av[2 * grp + 1]);
        *reinterpret_cast<float2*>(out + (size_t)node * CCH + sl * 8 + 2 * grp) = st;
    }
}

// ---------------- last-resort fallback: pure fp32 atomics (R1) ----------------

__global__ __launch_bounds__(256) void edge_gather_scatter(
    const float* __restrict__ x, const int* __restrict__ edge_index,
    const float* __restrict__ W2, const float* __restrict__ W3,
    float* __restrict__ out, int E)
{
    const int e    = (blockIdx.x * blockDim.x + threadIdx.x) >> 6;
    const int lane = threadIdx.x & 63;
    if (e >= E) return;
    const int s = edge_index[e];
    const int d = edge_index[E + e];
    const float2 xs = *reinterpret_cast<const float2*>(x + (size_t)s * CCH + lane * 2);
    const float2 xd = *reinterpret_cast<const float2*>(x + (size_t)d * CCH + lane * 2);
    const float2 w3 = *reinterpret_cast<const float2*>(W3 + lane * 2);
    const float2 w2 = *reinterpret_cast<const float2*>(W2 + lane * 2);
    float p = xs.x * w3.x * xd.x + xs.y * w3.y * xd.y;
    #pragma unroll
    for (int off = 32; off > 0; off >>= 1) p += __shfl_xor(p, off, 64);
    float* o = out + (size_t)d * CCH + lane * 2;
    atomicAdd(o,     p * xs.x * w2.x);
    atomicAdd(o + 1, p * xs.y * w2.y);
}

// ---------------- launch ----------------

extern "C" void kernel_launch(void* const* d_in, const int* in_sizes, int n_in,
                              void* d_out, int out_size, void* d_ws, size_t ws_size,
                              hipStream_t stream) {
    const float* x          = (const float*)d_in[0];
    const int*   edge_index = (const int*)  d_in[1];
    const float* W2         = (const float*)d_in[2];
    const float* W3         = (const float*)d_in[3];
    float*       out        = (float*)d_out;

    const int E = in_sizes[1] / 2;
    const int N = out_size / CCH;
    const int* src = edge_index;
    const int* dst = edge_index + E;

    const int NBIN = (N + BWIDTH - 1) >> BSHIFT;
    const int NBLK = (E + CH - 1) / CH;
    const long long Mll = (long long)NBIN * NBLK;
    const int M = (int)Mll;
    const int nb1 = (M + SCAN_TILE - 1) / SCAN_TILE;

    const size_t xh_bytes = (size_t)N * CCH * 2;
    const size_t need = xh_bytes + (size_t)E * 4 + 2 * (size_t)M * 4 + 1024 * 4;

    const bool aligned16 = (((uintptr_t)src & 15) == 0) && (((uintptr_t)dst & 15) == 0);

    if (N <= (1 << 17) && NBIN <= MAXBIN && Mll <= (1LL << 20) && nb1 <= 1024 &&
        aligned16 && ws_size >= need) {
        char* base = (char*)d_ws;
        __half* xh       = (__half*)base;        base += xh_bytes;
        unsigned* coarse = (unsigned*)base;      base += (size_t)E * 4;
        int* hist_bm     = (int*)base;           base += (size_t)M * 4;
        int* partial     = (int*)base;           base += (size_t)M * 4;
        int* blocksum    = (int*)base;

        const int n4 = N * CCH / 4;
        const int nPack = (n4 + 255) / 256;

        k_pack_hist<<<nPack + NBLK, 256, 0, stream>>>(x, xh, n4, nPack,
                                                      dst, E, NBIN, hist_bm);
        k_pscan1<<<nb1, SCAN_BLOCK, 0, stream>>>(hist_bm, M, NBIN, NBLK, partial, blocksum);
        k_scan2<<<1, 1024, 0, stream>>>(blocksum, nb1);
        k_place<<<NBLK, 256, 0, stream>>>(src, dst, E, NBIN, NBLK,
                                          partial, blocksum, coarse);
        k_sort_accum<<<NBIN, 256, 0, stream>>>(xh, W2, W3, coarse,
                                               partial, blocksum,
                                               NBIN, NBLK, E, N, out);
        return;
    }

    // last resort: pure atomics
    hipMemsetAsync(d_out, 0, (size_t)out_size * sizeof(float), stream);
    const int grid = (E * 64 + 255) / 256;
    edge_gather_scatter<<<grid, 256, 0, stream>>>(x, edge_index, W2, W3, out, E);
}

// Round 8
// 125.540 us; speedup vs baseline: 10.5136x; 1.1745x over previous
//
#include <hip/hip_runtime.h>
#include <hip/hip_fp16.h>

// out[n,c] = sum_{e: dst[e]==n} ( sum_k x[src[e],k]*W3[k]*x[dst[e],k] ) * x[src[e],c] * W2[c]
// B=1, N=100000, E=1600000, C=128.
//
// Pipeline (5 launches, no global atomic-returns anywhere):
//   k_pack_hist : fused; x fp32->fp16 pack blocks + per-block coarse-bin
//                 histogram blocks (bin = dst>>5)
//   k_pscan1/2  : exclusive scan of bin-major (bin,block) counts
//   k_place     : deterministic placement of packed (dstlow|src) into bins
//   k_sort_accum: per-bin LDS counting sort by dstlow + fused accumulation.
//                 R8: each 16-lane group owns ONE node (4 independent nodes
//                 per wave, 2 nodes/group serially), 4-deep edge unroll ->
//                 16 gathers in flight per wave; no replica-combine shfls.
// Fallback: R1-style pure-atomic kernel if constraints unmet.

#define CCH 128
#define BSHIFT 5
#define BWIDTH 32              // nodes per bin
#define MAXBIN 4096            // supports N <= 131072 (17-bit src pack)
#define CH 8192                // edges per partition block
#define LDSCAP 1280            // max edges staged per bin (mean ~512)
#define SCAN_BLOCK 256
#define SCAN_ITEMS 4
#define SCAN_TILE (SCAN_BLOCK * SCAN_ITEMS)

// ---------------- fused fp16 pack + per-block bin histogram ----------------

__global__ __launch_bounds__(256) void k_pack_hist(
    const float* __restrict__ x, __half* __restrict__ xh, int n4, int nPack,
    const int* __restrict__ dst, int E, int NBIN, int* __restrict__ hist_bm)
{
    __shared__ int cnt[MAXBIN];
    const int tid = threadIdx.x;

    if (blockIdx.x < nPack) {                 // pack role
        const int i = blockIdx.x * 256 + tid;
        if (i < n4) {
            float4 v = reinterpret_cast<const float4*>(x)[i];
            __half2* o = reinterpret_cast<__half2*>(xh) + (size_t)i * 2;
            o[0] = __floats2half2_rn(v.x, v.y);
            o[1] = __floats2half2_rn(v.z, v.w);
        }
        return;
    }

    const int blk = blockIdx.x - nPack;       // histogram role
    for (int b = tid; b < NBIN; b += 256) cnt[b] = 0;
    __syncthreads();

    const int e0 = blk * CH;
    #pragma unroll
    for (int k = 0; k < CH / 1024; ++k) {
        const int g = (e0 >> 2) + k * 256 + tid;   // int4 index
        const int e = g << 2;
        if (e >= E) continue;
        if (e + 4 <= E) {
            const int4 d4 = reinterpret_cast<const int4*>(dst)[g];
            atomicAdd(&cnt[d4.x >> BSHIFT], 1);
            atomicAdd(&cnt[d4.y >> BSHIFT], 1);
            atomicAdd(&cnt[d4.z >> BSHIFT], 1);
            atomicAdd(&cnt[d4.w >> BSHIFT], 1);
        } else {
            for (int ee = e; ee < E; ++ee) atomicAdd(&cnt[dst[ee] >> BSHIFT], 1);
        }
    }
    __syncthreads();
    int* hb = hist_bm + (size_t)blk * NBIN;
    for (int b = tid; b < NBIN; b += 256) hb[b] = cnt[b];
}

// ---------------- scan over bin-major flatten ----------------

__global__ void k_pscan1(const int* __restrict__ hist_bm, int M, int NBIN, int NBLK,
                         int* __restrict__ partial, int* __restrict__ blocksum) {
    __shared__ int sdata[SCAN_BLOCK];
    const int base = blockIdx.x * SCAN_TILE;
    const int t = threadIdx.x;
    int v[SCAN_ITEMS];
    int local = 0;
    #pragma unroll
    for (int k = 0; k < SCAN_ITEMS; ++k) {
        int idx = base + t * SCAN_ITEMS + k;
        int val = 0;
        if (idx < M) {
            int bin = idx / NBLK, blk = idx % NBLK;
            val = hist_bm[(size_t)blk * NBIN + bin];
        }
        v[k] = val;
        local += val;
    }
    sdata[t] = local;
    __syncthreads();
    #pragma unroll
    for (int off = 1; off < SCAN_BLOCK; off <<= 1) {
        int val = (t >= off) ? sdata[t - off] : 0;
        __syncthreads();
        sdata[t] += val;
        __syncthreads();
    }
    const int incl = sdata[t];
    int run = incl - local;
    if (t == SCAN_BLOCK - 1) blocksum[blockIdx.x] = incl;
    #pragma unroll
    for (int k = 0; k < SCAN_ITEMS; ++k) {
        int idx = base + t * SCAN_ITEMS + k;
        if (idx < M) partial[idx] = run;
        run += v[k];
    }
}

__global__ void k_scan2(int* __restrict__ blocksum, int nb) {
    __shared__ int sdata[1024];
    const int t = threadIdx.x;
    const int v = (t < nb) ? blocksum[t] : 0;
    sdata[t] = v;
    __syncthreads();
    for (int off = 1; off < 1024; off <<= 1) {
        int val = (t >= off) ? sdata[t - off] : 0;
        __syncthreads();
        sdata[t] += val;
        __syncthreads();
    }
    if (t < nb) blocksum[t] = sdata[t] - v;
}

// ---------------- deterministic placement ----------------

__global__ __launch_bounds__(256) void k_place(
    const int* __restrict__ src, const int* __restrict__ dst, int E, int NBIN, int NBLK,
    const int* __restrict__ partial, const int* __restrict__ blocksum,
    unsigned int* __restrict__ coarse)
{
    __shared__ int lcur[MAXBIN];
    const int blk = blockIdx.x;
    const int tid = threadIdx.x;
    for (int b = tid; b < NBIN; b += 256) {
        const size_t idx = (size_t)b * NBLK + blk;
        lcur[b] = partial[idx] + blocksum[idx / SCAN_TILE];
    }
    __syncthreads();

    const int e0 = blk * CH;
    #pragma unroll
    for (int k = 0; k < CH / 1024; ++k) {
        const int g = (e0 >> 2) + k * 256 + tid;
        const int e = g << 2;
        if (e >= E) continue;
        if (e + 4 <= E) {
            const int4 d4 = reinterpret_cast<const int4*>(dst)[g];
            const int4 s4 = reinterpret_cast<const int4*>(src)[g];
            int p;
            p = atomicAdd(&lcur[d4.x >> BSHIFT], 1);
            coarse[p] = (unsigned)s4.x | ((unsigned)(d4.x & (BWIDTH - 1)) << 17);
            p = atomicAdd(&lcur[d4.y >> BSHIFT], 1);
            coarse[p] = (unsigned)s4.y | ((unsigned)(d4.y & (BWIDTH - 1)) << 17);
            p = atomicAdd(&lcur[d4.z >> BSHIFT], 1);
            coarse[p] = (unsigned)s4.z | ((unsigned)(d4.z & (BWIDTH - 1)) << 17);
            p = atomicAdd(&lcur[d4.w >> BSHIFT], 1);
            coarse[p] = (unsigned)s4.w | ((unsigned)(d4.w & (BWIDTH - 1)) << 17);
        } else {
            for (int ee = e; ee < E; ++ee) {
                const int d = dst[ee], s = src[ee];
                int p = atomicAdd(&lcur[d >> BSHIFT], 1);
                coarse[p] = (unsigned)s | ((unsigned)(d & (BWIDTH - 1)) << 17);
            }
        }
    }
}

// ---------------- per-bin LDS counting sort + fused accumulation ----------------
// R8 layout: 16 groups of 16 lanes per block; group gid owns nodes
// gid*2, gid*2+1 of the bin. Lane sl owns channels sl*8..sl*8+7 (16B fp16).
// shfl_xor offsets 1,2,4,8 reduce entirely within a group -> 4 independent
// node chains per wave, 4-deep edge unroll -> 16 gathers in flight per wave.

__global__ __launch_bounds__(256) void k_sort_accum(
    const __half* __restrict__ xh,
    const float* __restrict__ W2,
    const float* __restrict__ W3,
    const unsigned int* __restrict__ coarse,
    const int* __restrict__ partial, const int* __restrict__ blocksum,
    int NBIN, int NBLK, int E, int N,
    float* __restrict__ out)
{
    __shared__ unsigned int raw[LDSCAP];
    __shared__ int srcl[LDSCAP];
    __shared__ int cnt[BWIDTH], offs[BWIDTH], cur[BWIDTH];

    const int bin = blockIdx.x;
    const int tid = threadIdx.x;
    const size_t i0 = (size_t)bin * NBLK;
    const int beg = partial[i0] + blocksum[i0 / SCAN_TILE];
    const int end = (bin + 1 < NBIN)
        ? partial[i0 + NBLK] + blocksum[(i0 + NBLK) / SCAN_TILE] : E;
    const int mtot = end - beg;
    const int m = (mtot < LDSCAP) ? mtot : LDSCAP;

    if (tid < BWIDTH) cnt[tid] = 0;
    __syncthreads();

    for (int i = tid; i < m; i += 256) {
        unsigned u = coarse[beg + i];
        raw[i] = u;
        atomicAdd(&cnt[u >> 17], 1);
    }
    __syncthreads();

    if (tid < BWIDTH) {          // lanes 0..31 of wave 0: exclusive scan
        int c = cnt[tid];
        int v = c;
        #pragma unroll
        for (int d2 = 1; d2 < BWIDTH; d2 <<= 1) {
            int t2 = __shfl_up(v, d2, 64);
            if (tid >= d2) v += t2;
        }
        offs[tid] = v - c;
        cur[tid]  = v - c;
    }
    __syncthreads();

    for (int i = tid; i < m; i += 256) {
        unsigned u = raw[i];
        int p = atomicAdd(&cur[u >> 17], 1);
        srcl[p] = (int)(u & 0x1FFFFu);
    }
    __syncthreads();

    const int lane = tid & 63;
    const int grp  = lane >> 4;              // group within wave 0..3
    const int sl   = lane & 15;              // channel slot
    const int gid  = (tid >> 6) * 4 + grp;   // global group 0..15

    const float4 w3a = *reinterpret_cast<const float4*>(W3 + sl * 8);
    const float4 w3b = *reinterpret_cast<const float4*>(W3 + sl * 8 + 4);
    const float4 w2a = *reinterpret_cast<const float4*>(W2 + sl * 8);
    const float4 w2b = *reinterpret_cast<const float4*>(W2 + sl * 8 + 4);

    const char* xb = (const char*)xh;
    const int choff = sl << 4;               // byte offset of lane's 16B in a row

    #pragma unroll
    for (int i = 0; i < BWIDTH / 16; ++i) {  // 2 nodes per group
        const int dl = gid * (BWIDTH / 16) + i;
        const int node = (bin << BSHIFT) + dl;
        if (node < N) {
            // v = W3 .* x[node] for this lane's 8 channels (dst row via fp16 xh)
            union { int4 i4; __half2 h[4]; } uD;
            uD.i4 = *reinterpret_cast<const int4*>(xb + (((size_t)node) << 8) + choff);
            const float2 e0 = __half22float2(uD.h[0]);
            const float2 e1 = __half22float2(uD.h[1]);
            const float2 e2 = __half22float2(uD.h[2]);
            const float2 e3 = __half22float2(uD.h[3]);
            const float4 va = make_float4(w3a.x * e0.x, w3a.y * e0.y,
                                          w3a.z * e1.x, w3a.w * e1.y);
            const float4 vb = make_float4(w3b.x * e2.x, w3b.y * e2.y,
                                          w3b.z * e3.x, w3b.w * e3.y);

            float4 accA = make_float4(0.f, 0.f, 0.f, 0.f);
            float4 accB = make_float4(0.f, 0.f, 0.f, 0.f);

            const int b0 = offs[dl];
            const int c  = cnt[dl];

            int j = 0;
            for (; j + 4 <= c; j += 4) {     // 4 gathers in flight per group
                const int s0 = srcl[b0 + j];
                const int s1 = srcl[b0 + j + 1];
                const int s2 = srcl[b0 + j + 2];
                const int s3 = srcl[b0 + j + 3];
                union { int4 i4; __half2 h[4]; } u0, u1, u2, u3;
                u0.i4 = *reinterpret_cast<const int4*>(xb + (((size_t)s0) << 8) + choff);
                u1.i4 = *reinterpret_cast<const int4*>(xb + (((size_t)s1) << 8) + choff);
                u2.i4 = *reinterpret_cast<const int4*>(xb + (((size_t)s2) << 8) + choff);
                u3.i4 = *reinterpret_cast<const int4*>(xb + (((size_t)s3) << 8) + choff);
                const float2 f00 = __half22float2(u0.h[0]);
                const float2 f01 = __half22float2(u0.h[1]);
                const float2 f02 = __half22float2(u0.h[2]);
                const float2 f03 = __half22float2(u0.h[3]);
                const float2 f10 = __half22float2(u1.h[0]);
                const float2 f11 = __half22float2(u1.h[1]);
                const float2 f12 = __half22float2(u1.h[2]);
                const float2 f13 = __half22float2(u1.h[3]);
                const float2 f20 = __half22float2(u2.h[0]);
                const float2 f21 = __half22float2(u2.h[1]);
                const float2 f22 = __half22float2(u2.h[2]);
                const float2 f23 = __half22float2(u2.h[3]);
                const float2 f30 = __half22float2(u3.h[0]);
                const float2 f31 = __half22float2(u3.h[1]);
                const float2 f32 = __half22float2(u3.h[2]);
                const float2 f33 = __half22float2(u3.h[3]);
                float p0 = f00.x * va.x + f00.y * va.y + f01.x * va.z + f01.y * va.w
                         + f02.x * vb.x + f02.y * vb.y + f03.x * vb.z + f03.y * vb.w;
                float p1 = f10.x * va.x + f10.y * va.y + f11.x * va.z + f11.y * va.w
                         + f12.x * vb.x + f12.y * vb.y + f13.x * vb.z + f13.y * vb.w;
                float p2 = f20.x * va.x + f20.y * va.y + f21.x * va.z + f21.y * va.w
                         + f22.x * vb.x + f22.y * vb.y + f23.x * vb.z + f23.y * vb.w;
                float p3 = f30.x * va.x + f30.y * va.y + f31.x * va.z + f31.y * va.w
                         + f32.x * vb.x + f32.y * vb.y + f33.x * vb.z + f33.y * vb.w;
                #pragma unroll
                for (int off = 1; off < 16; off <<= 1) {   // within-group reduce
                    p0 += __shfl_xor(p0, off, 64);
                    p1 += __shfl_xor(p1, off, 64);
                    p2 += __shfl_xor(p2, off, 64);
                    p3 += __shfl_xor(p3, off, 64);
                }
                accA.x += p0 * f00.x + p1 * f10.x + p2 * f20.x + p3 * f30.x;
                accA.y += p0 * f00.y + p1 * f10.y + p2 * f20.y + p3 * f30.y;
                accA.z += p0 * f01.x + p1 * f11.x + p2 * f21.x + p3 * f31.x;
                accA.w += p0 * f01.y + p1 * f11.y + p2 * f21.y + p3 * f31.y;
                accB.x += p0 * f02.x + p1 * f12.x + p2 * f22.x + p3 * f32.x;
                accB.y += p0 * f02.y + p1 * f12.y + p2 * f22.y + p3 * f32.y;
                accB.z += p0 * f03.x + p1 * f13.x + p2 * f23.x + p3 * f33.x;
                accB.w += p0 * f03.y + p1 * f13.y + p2 * f23.y + p3 * f33.y;
            }
            for (; j < c; ++j) {             // remainder, whole group active
                const int s0 = srcl[b0 + j];
                union { int4 i4; __half2 h[4]; } u0;
                u0.i4 = *reinterpret_cast<const int4*>(xb + (((size_t)s0) << 8) + choff);
                const float2 f0 = __half22float2(u0.h[0]);
                const float2 f1 = __half22float2(u0.h[1]);
                const float2 f2 = __half22float2(u0.h[2]);
                const float2 f3 = __half22float2(u0.h[3]);
                float p = f0.x * va.x + f0.y * va.y + f1.x * va.z + f1.y * va.w
                        + f2.x * vb.x + f2.y * vb.y + f3.x * vb.z + f3.y * vb.w;
                #pragma unroll
                for (int off = 1; off < 16; off <<= 1) p += __shfl_xor(p, off, 64);
                accA.x += p * f0.x;
                accA.y += p * f0.y;
                accA.z += p * f1.x;
                accA.w += p * f1.y;
                accB.x += p * f2.x;
                accB.y += p * f2.y;
                accB.z += p * f3.x;
                accB.w += p * f3.y;
            }
            // LDS-capacity overflow (normally zero iterations)
            for (int i2 = LDSCAP; i2 < mtot; ++i2) {
                const unsigned u = coarse[beg + i2];
                if ((int)(u >> 17) != dl) continue;
                const int s0 = (int)(u & 0x1FFFFu);
                union { int4 i4; __half2 h[4]; } u0;
                u0.i4 = *reinterpret_cast<const int4*>(xb + (((size_t)s0) << 8) + choff);
                const float2 f0 = __half22float2(u0.h[0]);
                const float2 f1 = __half22float2(u0.h[1]);
                const float2 f2 = __half22float2(u0.h[2]);
                const float2 f3 = __half22float2(u0.h[3]);
                float p = f0.x * va.x + f0.y * va.y + f1.x * va.z + f1.y * va.w
                        + f2.x * vb.x + f2.y * vb.y + f3.x * vb.z + f3.y * vb.w;
                #pragma unroll
                for (int off = 1; off < 16; off <<= 1) p += __shfl_xor(p, off, 64);
                accA.x += p * f0.x;
                accA.y += p * f0.y;
                accA.z += p * f1.x;
                accA.w += p * f1.y;
                accB.x += p * f2.x;
                accB.y += p * f2.y;
                accB.z += p * f3.x;
                accB.w += p * f3.y;
            }

            // apply W2; lane sl writes channels sl*8..sl*8+7 (group: 512B row)
            accA.x *= w2a.x; accA.y *= w2a.y; accA.z *= w2a.z; accA.w *= w2a.w;
            accB.x *= w2b.x; accB.y *= w2b.y; accB.z *= w2b.z; accB.w *= w2b.w;
            float* orow = out + (size_t)node * CCH + sl * 8;
            *reinterpret_cast<float4*>(orow)     = accA;
            *reinterpret_cast<float4*>(orow + 4) = accB;
        }
    }
}

// ---------------- last-resort fallback: pure fp32 atomics (R1) ----------------

__global__ __launch_bounds__(256) void edge_gather_scatter(
    const float* __restrict__ x, const int* __restrict__ edge_index,
    const float* __restrict__ W2, const float* __restrict__ W3,
    float* __restrict__ out, int E)
{
    const int e    = (blockIdx.x * blockDim.x + threadIdx.x) >> 6;
    const int lane = threadIdx.x & 63;
    if (e >= E) return;
    const int s = edge_index[e];
    const int d = edge_index[E + e];
    const float2 xs = *reinterpret_cast<const float2*>(x + (size_t)s * CCH + lane * 2);
    const float2 xd = *reinterpret_cast<const float2*>(x + (size_t)d * CCH + lane * 2);
    const float2 w3 = *reinterpret_cast<const float2*>(W3 + lane * 2);
    const float2 w2 = *reinterpret_cast<const float2*>(W2 + lane * 2);
    float p = xs.x * w3.x * xd.x + xs.y * w3.y * xd.y;
    #pragma unroll
    for (int off = 32; off > 0; off >>= 1) p += __shfl_xor(p, off, 64);
    float* o = out + (size_t)d * CCH + lane * 2;
    atomicAdd(o,     p * xs.x * w2.x);
    atomicAdd(o + 1, p * xs.y * w2.y);
}

// ---------------- launch ----------------

extern "C" void kernel_launch(void* const* d_in, const int* in_sizes, int n_in,
                              void* d_out, int out_size, void* d_ws, size_t ws_size,
                              hipStream_t stream) {
    const float* x          = (const float*)d_in[0];
    const int*   edge_index = (const int*)  d_in[1];
    const float* W2         = (const float*)d_in[2];
    const float* W3         = (const float*)d_in[3];
    float*       out        = (float*)d_out;

    const int E = in_sizes[1] / 2;
    const int N = out_size / CCH;
    const int* src = edge_index;
    const int* dst = edge_index + E;

    const int NBIN = (N + BWIDTH - 1) >> BSHIFT;
    const int NBLK = (E + CH - 1) / CH;
    const long long Mll = (long long)NBIN * NBLK;
    const int M = (int)Mll;
    const int nb1 = (M + SCAN_TILE - 1) / SCAN_TILE;

    const size_t xh_bytes = (size_t)N * CCH * 2;
    const size_t need = xh_bytes + (size_t)E * 4 + 2 * (size_t)M * 4 + 1024 * 4;

    const bool aligned16 = (((uintptr_t)src & 15) == 0) && (((uintptr_t)dst & 15) == 0);

    if (N <= (1 << 17) && NBIN <= MAXBIN && Mll <= (1LL << 20) && nb1 <= 1024 &&
        aligned16 && ws_size >= need) {
        char* base = (char*)d_ws;
        __half* xh       = (__half*)base;        base += xh_bytes;
        unsigned* coarse = (unsigned*)base;      base += (size_t)E * 4;
        int* hist_bm     = (int*)base;           base += (size_t)M * 4;
        int* partial     = (int*)base;           base += (size_t)M * 4;
        int* blocksum    = (int*)base;

        const int n4 = N * CCH / 4;
        const int nPack = (n4 + 255) / 256;

        k_pack_hist<<<nPack + NBLK, 256, 0, stream>>>(x, xh, n4, nPack,
                                                      dst, E, NBIN, hist_bm);
        k_pscan1<<<nb1, SCAN_BLOCK, 0, stream>>>(hist_bm, M, NBIN, NBLK, partial, blocksum);
        k_scan2<<<1, 1024, 0, stream>>>(blocksum, nb1);
        k_place<<<NBLK, 256, 0, stream>>>(src, dst, E, NBIN, NBLK,
                                          partial, blocksum, coarse);
        k_sort_accum<<<NBIN, 256, 0, stream>>>(xh, W2, W3, coarse,
                                               partial, blocksum,
                                               NBIN, NBLK, E, N, out);
        return;
    }

    // last resort: pure atomics
    hipMemsetAsync(d_out, 0, (size_t)out_size * sizeof(float), stream);
    const int grid = (E * 64 + 255) / 256;
    edge_gather_scatter<<<grid, 256, 0, stream>>>(x, edge_index, W2, W3, out, E);
}